// Round 5
// baseline (1581.305 us; speedup 1.0000x reference)
//
#include <hip/hip_runtime.h>
#include <hip/hip_bf16.h>

#define N_NODES 100000
#define N_EDGES 1000000
#define DIM 64
#define N_GRAPHS 256
#define OUT_DIM 10
#define BN_EPS 1e-5f

#define POOL_BLOCKS 512                      // 2048 waves
#define MLP_BLOCKS ((N_NODES + 63) / 64)     // 1563

// Edge binning: 128 dst-nodes per bucket.
#define BSHIFT 7
#define NBUCK ((N_NODES + 127) / 128)        // 782
#define BCAP 1664                            // mean 1280 + ~10 sigma
#define EPB 4096                             // edges per bin block
#define BIN_BLOCKS ((N_EDGES + EPB - 1) / EPB)  // 245

typedef __bf16 bf16x8 __attribute__((ext_vector_type(8)));
typedef float f32x4 __attribute__((ext_vector_type(4)));

// ---------------------------------------------------------------------------
// Edge binning (once per call): counting-sort 4096-edge tiles in LDS into
// NBUCK coarse buckets, then flush contiguous per-bucket runs (~10 records)
// with one global cursor atomic each. Record = src<<7 | (dst&127).
// Kills the 16x write amplification of per-edge scatter (69 MB -> ~6 MB).
// ---------------------------------------------------------------------------
__global__ __launch_bounds__(256) void bin_kernel(
    const int* __restrict__ ei, int* __restrict__ gcur,
    unsigned* __restrict__ ebin)
{
    __shared__ int cnt[NBUCK];
    __shared__ int offs[NBUCK];
    __shared__ int fill[NBUCK];
    __shared__ int gbase[NBUCK];
    __shared__ int sa[NBUCK];
    __shared__ int sb[NBUCK];
    __shared__ uint2 rec[EPB];               // (packed, bucket), 32 KB

    const int t = threadIdx.x;
    const int e0 = blockIdx.x * EPB;
    const int ne = min(EPB, N_EDGES - e0);

    for (int i = t; i < NBUCK; i += 256) { cnt[i] = 0; fill[i] = 0; }
    __syncthreads();

    // load edges into registers + LDS histogram
    int srcs[16], dsts[16];
#pragma unroll
    for (int j = 0; j < 16; ++j) {
        int i = j * 256 + t;                  // coalesced
        if (i < ne) {
            srcs[j] = ei[e0 + i];
            dsts[j] = ei[N_EDGES + e0 + i];
            atomicAdd(&cnt[dsts[j] >> BSHIFT], 1);
        }
    }
    __syncthreads();

    // exclusive scan of cnt -> offs (double-buffered Hillis-Steele)
    for (int i = t; i < NBUCK; i += 256) sa[i] = cnt[i];
    __syncthreads();
    int* from = sa; int* to = sb;
    for (int off = 1; off < NBUCK; off <<= 1) {
        for (int i = t; i < NBUCK; i += 256)
            to[i] = from[i] + (i >= off ? from[i - off] : 0);
        __syncthreads();
        int* tmp = from; from = to; to = tmp;
    }
    for (int i = t; i < NBUCK; i += 256) offs[i] = from[i] - cnt[i];
    __syncthreads();

    // reorder into rec (bucket-sorted within tile)
#pragma unroll
    for (int j = 0; j < 16; ++j) {
        int i = j * 256 + t;
        if (i < ne) {
            int b = dsts[j] >> BSHIFT;
            int p = offs[b] + atomicAdd(&fill[b], 1);
            rec[p] = make_uint2(((unsigned)srcs[j] << BSHIFT) |
                                ((unsigned)dsts[j] & 127u), (unsigned)b);
        }
    }
    __syncthreads();

    // reserve global space per bucket
    for (int b = t; b < NBUCK; b += 256)
        if (cnt[b] > 0) gbase[b] = atomicAdd(&gcur[b], cnt[b]);
    __syncthreads();

    // flush runs (consecutive i within a bucket -> consecutive global slots)
    for (int i = t; i < ne; i += 256) {
        uint2 r = rec[i];
        int b = (int)r.y;
        ebin[(size_t)b * BCAP + gbase[b] + (i - offs[b])] = r.x;
    }
}

// ---------------------------------------------------------------------------
// BN prep: per-dim affine from accumulated sum/sumsq.
// sc[0..63] = scale, sc[64..127] = shift.  y = relu(scale*v + shift)
// ---------------------------------------------------------------------------
__global__ __launch_bounds__(64) void bnprep_kernel(
    const float* __restrict__ sums, const float* __restrict__ gamma,
    const float* __restrict__ beta, float* __restrict__ sc)
{
    int d = threadIdx.x;
    const float inv_n = 1.0f / (float)N_NODES;
    float mean = sums[d] * inv_n;
    float m2 = sums[64 + d] * inv_n;
    float var = m2 - mean * mean;
    float scale = gamma[d] * rsqrtf(var + BN_EPS);
    sc[d] = scale;
    sc[64 + d] = fmaf(-mean, scale, beta[d]);
}

// ---------------------------------------------------------------------------
// Weight prep: split each 64x64 fp32 W into bf16 hi/lo, stored in MFMA
// B-fragment order: blob[(kstep*4+ntile)*64 + lane][j]; hi at +0, lo at +4096.
// ---------------------------------------------------------------------------
__global__ __launch_bounds__(256) void wprep_kernel(
    const float* __restrict__ w1, const float* __restrict__ w2,
    __bf16* __restrict__ wf)
{
    int L = blockIdx.x >> 1, mat = blockIdx.x & 1;
    const float* w = (mat ? w2 : w1) + L * 4096;
    __bf16* dst = wf + blockIdx.x * 8192;
#pragma unroll
    for (int r = 0; r < 2; ++r) {
        int idx = threadIdx.x + 256 * r;          // (kstep*4+nt)*64 + lane
        int lane = idx & 63;
        int kt = idx >> 6;
        int kstep = kt >> 2, nt = kt & 3;
        int n = nt * 16 + (lane & 15);
        int kbase = kstep * 32 + (lane >> 4) * 8;
#pragma unroll
        for (int j = 0; j < 8; ++j) {
            float v = w[(kbase + j) * 64 + n];
            __bf16 hi = (__bf16)v;
            dst[idx * 8 + j] = hi;
            dst[4096 + idx * 8 + j] = (__bf16)(v - (float)hi);
        }
    }
}

// ---------------------------------------------------------------------------
// Aggregation from binned edges: one block per bucket (128 dst nodes),
// 32 KB LDS accumulator (lane = dim -> 2-way bank aliasing, free).
// Per edge: broadcast record read + coalesced 256B x[src] row + ds_add.
// Optionally applies previous layer's BN affine + relu to gathered values.
// ---------------------------------------------------------------------------
template <bool BN>
__global__ __launch_bounds__(512) void agg_kernel(
    const float* __restrict__ x, const float* __restrict__ sc,
    const int* __restrict__ gcur, const unsigned* __restrict__ ebin,
    float* __restrict__ agg)
{
    __shared__ float acc[128 * 64];              // 32 KB
    const int b = blockIdx.x;
    const int node0 = b << BSHIFT;
    const int nn = min(128, N_NODES - node0);
    const int t = threadIdx.x;
    const int lane = t & 63;
    const int wv = t >> 6;                       // 8 waves

    for (int i = t; i < 128 * 64 / 4; i += 512)
        ((float4*)acc)[i] = make_float4(0.f, 0.f, 0.f, 0.f);
    __syncthreads();

    float scale = 1.0f, shift = 0.0f;
    if (BN) { scale = sc[lane]; shift = sc[64 + lane]; }

    const int cntb = gcur[b];
    const unsigned* eb = ebin + (size_t)b * BCAP;

    int e = wv;
    for (; e + 24 < cntb; e += 32) {             // 8 waves x unroll 4
        unsigned r0 = eb[e], r1 = eb[e + 8], r2 = eb[e + 16], r3 = eb[e + 24];
        float v0 = x[(size_t)(r0 >> BSHIFT) * 64 + lane];
        float v1 = x[(size_t)(r1 >> BSHIFT) * 64 + lane];
        float v2 = x[(size_t)(r2 >> BSHIFT) * 64 + lane];
        float v3 = x[(size_t)(r3 >> BSHIFT) * 64 + lane];
        if (BN) {
            v0 = fmaxf(fmaf(v0, scale, shift), 0.0f);
            v1 = fmaxf(fmaf(v1, scale, shift), 0.0f);
            v2 = fmaxf(fmaf(v2, scale, shift), 0.0f);
            v3 = fmaxf(fmaf(v3, scale, shift), 0.0f);
        }
        atomicAdd(&acc[((r0 & 127u) << 6) + lane], v0);
        atomicAdd(&acc[((r1 & 127u) << 6) + lane], v1);
        atomicAdd(&acc[((r2 & 127u) << 6) + lane], v2);
        atomicAdd(&acc[((r3 & 127u) << 6) + lane], v3);
    }
    for (; e < cntb; e += 8) {
        unsigned r = eb[e];
        float v = x[(size_t)(r >> BSHIFT) * 64 + lane];
        if (BN) v = fmaxf(fmaf(v, scale, shift), 0.0f);
        atomicAdd(&acc[((r & 127u) << 6) + lane], v);
    }
    __syncthreads();

    for (int n = wv; n < nn; n += 8)
        agg[(size_t)(node0 + n) * 64 + lane] = acc[(n << 6) + lane];
}

// ---------------------------------------------------------------------------
// MFMA GIN MLP. Block = 4 waves; wave handles 16 nodes x all 64 output dims.
// h = (1+eps)*bn(x) + agg (agg read from h2buf, h2 written back in place).
// Each GEMM (K=64): fp32 split into bf16 hi/lo, 3 MFMA products.
// ---------------------------------------------------------------------------
template <bool BN>
__global__ __launch_bounds__(256) void mlp_mfma_kernel(
    const float* __restrict__ x, const float* __restrict__ sc,
    float* __restrict__ h2buf,
    const __bf16* __restrict__ wf1, const __bf16* __restrict__ wf2,
    const float* __restrict__ b1, const float* __restrict__ b2,
    const float* __restrict__ eps_all, int layer,
    float* __restrict__ sums)
{
    __shared__ __attribute__((aligned(16))) unsigned h1p[4][16][68];
    __shared__ float bnacc[128];

    const int tid = threadIdx.x;
    const int lane = tid & 63;
    const int wv = tid >> 6;
    const int q = lane >> 4;      // quad
    const int r = lane & 15;      // row-in-quad / col
    const int node0 = blockIdx.x * 64 + wv * 16;
    const bool active = node0 < N_NODES;

    if (tid < 128) bnacc[tid] = 0.0f;

    f32x4 acc[4];
    float bs[4], bq[4];
#pragma unroll
    for (int nt = 0; nt < 4; ++nt) {
        acc[nt] = (f32x4){0.f, 0.f, 0.f, 0.f};
        bs[nt] = 0.0f; bq[nt] = 0.0f;
    }

    if (active) {
        const float epsv = 1.0f + eps_all[layer];
#pragma unroll
        for (int kstep = 0; kstep < 2; ++kstep) {
            const int koff = kstep * 32 + q * 8;
            const float* xr = x + (size_t)(node0 + r) * 64 + koff;
            const float* ar = h2buf + (size_t)(node0 + r) * 64 + koff;
            float4 xa = *(const float4*)xr;
            float4 xb = *(const float4*)(xr + 4);
            float4 aa = *(const float4*)ar;
            float4 ab = *(const float4*)(ar + 4);
            float hv[8];
            const float* xap = (const float*)&xa;
            const float* xbp = (const float*)&xb;
            const float* aap = (const float*)&aa;
            const float* abp = (const float*)&ab;
            if (BN) {
                float4 s0 = *(const float4*)(sc + koff);
                float4 s1 = *(const float4*)(sc + koff + 4);
                float4 t0 = *(const float4*)(sc + 64 + koff);
                float4 t1 = *(const float4*)(sc + 64 + koff + 4);
                const float* s0p = (const float*)&s0;
                const float* s1p = (const float*)&s1;
                const float* t0p = (const float*)&t0;
                const float* t1p = (const float*)&t1;
#pragma unroll
                for (int j = 0; j < 4; ++j) {
                    float xv = fmaxf(fmaf(xap[j], s0p[j], t0p[j]), 0.0f);
                    hv[j] = fmaf(epsv, xv, aap[j]);
                    float xw = fmaxf(fmaf(xbp[j], s1p[j], t1p[j]), 0.0f);
                    hv[4 + j] = fmaf(epsv, xw, abp[j]);
                }
            } else {
#pragma unroll
                for (int j = 0; j < 4; ++j) {
                    hv[j] = fmaf(epsv, xap[j], aap[j]);
                    hv[4 + j] = fmaf(epsv, xbp[j], abp[j]);
                }
            }
            bf16x8 ahi, alo;
#pragma unroll
            for (int j = 0; j < 8; ++j) {
                __bf16 hi = (__bf16)hv[j];
                ahi[j] = hi;
                alo[j] = (__bf16)(hv[j] - (float)hi);
            }
#pragma unroll
            for (int nt = 0; nt < 4; ++nt) {
                const __bf16* bp = wf1 + ((kstep * 4 + nt) * 64 + lane) * 8;
                bf16x8 bhi = *(const bf16x8*)bp;
                bf16x8 blo = *(const bf16x8*)(bp + 4096);
                acc[nt] = __builtin_amdgcn_mfma_f32_16x16x32_bf16(ahi, bhi, acc[nt], 0, 0, 0);
                acc[nt] = __builtin_amdgcn_mfma_f32_16x16x32_bf16(alo, bhi, acc[nt], 0, 0, 0);
                acc[nt] = __builtin_amdgcn_mfma_f32_16x16x32_bf16(ahi, blo, acc[nt], 0, 0, 0);
            }
        }
#pragma unroll
        for (int nt = 0; nt < 4; ++nt) {
            float b1v = b1[nt * 16 + r];
#pragma unroll
            for (int reg = 0; reg < 4; ++reg) {
                float v = fmaxf(acc[nt][reg] + b1v, 0.0f);
                __bf16 hi = (__bf16)v;
                __bf16 lo = (__bf16)(v - (float)hi);
                unsigned pk = ((unsigned)__builtin_bit_cast(unsigned short, hi) << 16)
                            | (unsigned)__builtin_bit_cast(unsigned short, lo);
                h1p[wv][q * 4 + reg][nt * 16 + r] = pk;
            }
            acc[nt] = (f32x4){0.f, 0.f, 0.f, 0.f};
        }
    }
    __syncthreads();
    if (active) {
#pragma unroll
        for (int kstep = 0; kstep < 2; ++kstep) {
            uint4 p0 = *(const uint4*)&h1p[wv][r][kstep * 32 + q * 8];
            uint4 p1 = *(const uint4*)&h1p[wv][r][kstep * 32 + q * 8 + 4];
            unsigned pk[8] = {p0.x, p0.y, p0.z, p0.w, p1.x, p1.y, p1.z, p1.w};
            bf16x8 ahi, alo;
#pragma unroll
            for (int j = 0; j < 8; ++j) {
                ahi[j] = __builtin_bit_cast(__bf16, (unsigned short)(pk[j] >> 16));
                alo[j] = __builtin_bit_cast(__bf16, (unsigned short)(pk[j] & 0xffffu));
            }
#pragma unroll
            for (int nt = 0; nt < 4; ++nt) {
                const __bf16* bp = wf2 + ((kstep * 4 + nt) * 64 + lane) * 8;
                bf16x8 bhi = *(const bf16x8*)bp;
                bf16x8 blo = *(const bf16x8*)(bp + 4096);
                acc[nt] = __builtin_amdgcn_mfma_f32_16x16x32_bf16(ahi, bhi, acc[nt], 0, 0, 0);
                acc[nt] = __builtin_amdgcn_mfma_f32_16x16x32_bf16(alo, bhi, acc[nt], 0, 0, 0);
                acc[nt] = __builtin_amdgcn_mfma_f32_16x16x32_bf16(ahi, blo, acc[nt], 0, 0, 0);
            }
        }
#pragma unroll
        for (int nt = 0; nt < 4; ++nt) {
            float b2v = b2[nt * 16 + r];
#pragma unroll
            for (int reg = 0; reg < 4; ++reg) {
                float v = fmaxf(acc[nt][reg] + b2v, 0.0f);
                h2buf[(size_t)(node0 + q * 4 + reg) * 64 + nt * 16 + r] = v;
                bs[nt] += v;
                bq[nt] = fmaf(v, v, bq[nt]);
            }
        }
    }
#pragma unroll
    for (int nt = 0; nt < 4; ++nt) {
        float s = bs[nt];
        s += __shfl_xor(s, 16);
        s += __shfl_xor(s, 32);
        float ss = bq[nt];
        ss += __shfl_xor(ss, 16);
        ss += __shfl_xor(ss, 32);
        if (q == 0) {
            atomicAdd(&bnacc[nt * 16 + r], s);
            atomicAdd(&bnacc[64 + nt * 16 + r], ss);
        }
    }
    __syncthreads();
    if (tid < 128) unsafeAtomicAdd(&sums[tid], bnacc[tid]);
}

// ---------------------------------------------------------------------------
// Segmented global mean pool (batch sorted): register-accumulate per graph,
// one atomic flush per boundary. Applies last layer's BN affine+relu on load.
// ---------------------------------------------------------------------------
__global__ __launch_bounds__(256) void pool_kernel(
    const float* __restrict__ h2, const float* __restrict__ sc,
    const int* __restrict__ batch,
    float* __restrict__ pooled, float* __restrict__ counts)
{
    const int lane = threadIdx.x & 63;
    const int w = blockIdx.x * 4 + (threadIdx.x >> 6);
    const int nw = POOL_BLOCKS * 4;
    const int npw = (N_NODES + nw - 1) / nw;
    int n0 = w * npw;
    if (n0 >= N_NODES) return;
    int n1 = n0 + npw;
    if (n1 > N_NODES) n1 = N_NODES;

    const float scale = sc[lane];
    const float shift = sc[64 + lane];

    int cur = batch[n0];
    float acc = 0.0f, cnt = 0.0f;
    for (int n = n0; n < n1; ++n) {
        int g = batch[n];                       // wave-uniform
        if (g != cur) {
            unsafeAtomicAdd(&pooled[cur * 64 + lane], acc);
            if (lane == 0) unsafeAtomicAdd(&counts[cur], cnt);
            acc = 0.0f; cnt = 0.0f; cur = g;
        }
        float v = h2[n * 64 + lane];
        v = fmaxf(fmaf(v, scale, shift), 0.0f);
        acc += v;
        cnt += 1.0f;
    }
    unsafeAtomicAdd(&pooled[cur * 64 + lane], acc);
    if (lane == 0) unsafeAtomicAdd(&counts[cur], cnt);
}

// ---------------------------------------------------------------------------
// Final linear.
// ---------------------------------------------------------------------------
__global__ __launch_bounds__(256) void final_kernel(
    const float* __restrict__ pooled, const float* __restrict__ counts,
    const float* __restrict__ lin_w, const float* __restrict__ lin_b,
    float* __restrict__ out)
{
    int t = blockIdx.x * 256 + threadIdx.x;
    if (t >= N_GRAPHS * OUT_DIM) return;
    int g = t / OUT_DIM;
    int o = t - g * OUT_DIM;
    float acc = 0.0f;
#pragma unroll 8
    for (int d = 0; d < 64; ++d)
        acc = fmaf(pooled[g * 64 + d], lin_w[d * OUT_DIM + o], acc);
    float c = fmaxf(counts[g], 1.0f);
    out[t] = acc / c + lin_b[o];
}

extern "C" void kernel_launch(void* const* d_in, const int* in_sizes, int n_in,
                              void* d_out, int out_size, void* d_ws, size_t ws_size,
                              hipStream_t stream)
{
    const float* x0    = (const float*)d_in[0];
    const int*   ei    = (const int*)d_in[1];
    const int*   batch = (const int*)d_in[2];
    const float* w1    = (const float*)d_in[3];
    const float* b1    = (const float*)d_in[4];
    const float* w2    = (const float*)d_in[5];
    const float* b2    = (const float*)d_in[6];
    const float* gamma = (const float*)d_in[7];
    const float* beta  = (const float*)d_in[8];
    const float* eps_g = (const float*)d_in[9];
    const float* lin_w = (const float*)d_in[10];
    const float* lin_b = (const float*)d_in[11];
    float* out = (float*)d_out;

    // Workspace layout.
    float* ws   = (float*)d_ws;
    float* A    = ws;                                // ping, 6.4M floats
    float* B    = ws + (size_t)N_NODES * 64;         // pong, 6.4M floats
    float* SUMS = ws + (size_t)2 * N_NODES * 64;     // 128
    float* SC   = SUMS + 128;                        // 3 * 128 (scale|shift)
    float* POOL = SC + 3 * 128;                      // 16384
    float* CNT  = POOL + N_GRAPHS * 64;              // 256
    __bf16*   WF   = (__bf16*)(CNT + N_GRAPHS);      // 6*8192 bf16 = 96 KB
    int*      GCUR = (int*)(WF + 6 * 8192);          // 782 (+pad)
    unsigned* EBIN = (unsigned*)(GCUR + 800);        // 782*1664 u32 = 5.2 MB

    // ---- once per call: weight fragments + edge binning ----
    wprep_kernel<<<6, 256, 0, stream>>>(w1, w2, WF);
    hipMemsetAsync(GCUR, 0, NBUCK * sizeof(int), stream);
    bin_kernel<<<BIN_BLOCKS, 256, 0, stream>>>(ei, GCUR, EBIN);

    // ---- 3 GIN layers (BN of layer L fused into consumers of layer L+1) ----
    // L0: x0 -> agg in A -> h2_0 in A
    hipMemsetAsync(SUMS, 0, 128 * sizeof(float), stream);
    agg_kernel<false><<<NBUCK, 512, 0, stream>>>(x0, nullptr, GCUR, EBIN, A);
    mlp_mfma_kernel<false><<<MLP_BLOCKS, 256, 0, stream>>>(
        x0, nullptr, A, WF, WF + 8192, b1, b2, eps_g, 0, SUMS);
    bnprep_kernel<<<1, 64, 0, stream>>>(SUMS, gamma, beta, SC);

    // L1: bn(A) -> agg in B -> h2_1 in B
    hipMemsetAsync(SUMS, 0, 128 * sizeof(float), stream);
    agg_kernel<true><<<NBUCK, 512, 0, stream>>>(A, SC, GCUR, EBIN, B);
    mlp_mfma_kernel<true><<<MLP_BLOCKS, 256, 0, stream>>>(
        A, SC, B, WF + 16384, WF + 24576, b1 + 64, b2 + 64, eps_g, 1, SUMS);
    bnprep_kernel<<<1, 64, 0, stream>>>(SUMS, gamma + 64, beta + 64, SC + 128);

    // L2: bn(B) -> agg in A -> h2_2 in A
    hipMemsetAsync(SUMS, 0, 128 * sizeof(float), stream);
    agg_kernel<true><<<NBUCK, 512, 0, stream>>>(B, SC + 128, GCUR, EBIN, A);
    mlp_mfma_kernel<true><<<MLP_BLOCKS, 256, 0, stream>>>(
        B, SC + 128, A, WF + 32768, WF + 40960, b1 + 128, b2 + 128, eps_g, 2, SUMS);
    bnprep_kernel<<<1, 64, 0, stream>>>(SUMS, gamma + 128, beta + 128, SC + 256);

    // ---- segmented pool (applies bn of L2) + linear ----
    hipMemsetAsync(POOL, 0, (N_GRAPHS * 64 + N_GRAPHS) * sizeof(float), stream);
    pool_kernel<<<POOL_BLOCKS, 256, 0, stream>>>(A, SC + 256, batch, POOL, CNT);
    final_kernel<<<(N_GRAPHS * OUT_DIM + 255) / 256, 256, 0, stream>>>(
        POOL, CNT, lin_w, lin_b, out);
}

// Round 6
// 467.144 us; speedup vs baseline: 3.3850x; 3.3850x over previous
//
#include <hip/hip_runtime.h>
#include <hip/hip_bf16.h>

#define N_NODES 100000
#define N_EDGES 1000000
#define DIM 64
#define N_GRAPHS 256
#define OUT_DIM 10
#define BN_EPS 1e-5f

#define POOL_BLOCKS 512                      // 2048 waves
#define MLP_BLOCKS ((N_NODES + 63) / 64)     // 1563
#define PAD 24                               // slots per node; P(deg>24)~4e-5
#define SPILL_CAP 8192

typedef __bf16 bf16x8 __attribute__((ext_vector_type(8)));
typedef float f32x4 __attribute__((ext_vector_type(4)));

// ---------------------------------------------------------------------------
// Edge fill (replaces hist+scan+bucket): one atomic-return per edge into
// fixed 24-slot per-node bins. Rare overflow (deg>24) goes to a spill list.
// deg[] doubles as cursor and final degree.
// ---------------------------------------------------------------------------
__global__ __launch_bounds__(256) void fill_kernel(
    const int* __restrict__ ei, int* __restrict__ deg,
    int* __restrict__ esrc, int* __restrict__ nspill, int* __restrict__ spill)
{
    int e = blockIdx.x * 256 + threadIdx.x;
    if (e >= N_EDGES) return;
    int src = ei[e];
    int dst = ei[N_EDGES + e];
    int pos = atomicAdd(&deg[dst], 1);
    if (pos < PAD) {
        esrc[dst * PAD + pos] = src;
    } else {
        int sp = atomicAdd(nspill, 1);
        if (sp < SPILL_CAP) { spill[2 * sp] = dst; spill[2 * sp + 1] = src; }
    }
}

// ---------------------------------------------------------------------------
// BN prep: per-dim affine from accumulated sum/sumsq.
// sc[0..63] = scale, sc[64..127] = shift.  y = relu(scale*v + shift)
// ---------------------------------------------------------------------------
__global__ __launch_bounds__(64) void bnprep_kernel(
    const float* __restrict__ sums, const float* __restrict__ gamma,
    const float* __restrict__ beta, float* __restrict__ sc)
{
    int d = threadIdx.x;
    const float inv_n = 1.0f / (float)N_NODES;
    float mean = sums[d] * inv_n;
    float m2 = sums[64 + d] * inv_n;
    float var = m2 - mean * mean;
    float scale = gamma[d] * rsqrtf(var + BN_EPS);
    sc[d] = scale;
    sc[64 + d] = fmaf(-mean, scale, beta[d]);
}

// ---------------------------------------------------------------------------
// Weight prep: split each 64x64 fp32 W into bf16 hi/lo, stored in MFMA
// B-fragment order: blob[(kstep*4+ntile)*64 + lane][j]; hi at +0, lo at +4096.
// ---------------------------------------------------------------------------
__global__ __launch_bounds__(256) void wprep_kernel(
    const float* __restrict__ w1, const float* __restrict__ w2,
    __bf16* __restrict__ wf)
{
    int L = blockIdx.x >> 1, mat = blockIdx.x & 1;
    const float* w = (mat ? w2 : w1) + L * 4096;
    __bf16* dst = wf + blockIdx.x * 8192;
#pragma unroll
    for (int r = 0; r < 2; ++r) {
        int idx = threadIdx.x + 256 * r;          // (kstep*4+nt)*64 + lane
        int lane = idx & 63;
        int kt = idx >> 6;
        int kstep = kt >> 2, nt = kt & 3;
        int n = nt * 16 + (lane & 15);
        int kbase = kstep * 32 + (lane >> 4) * 8;
#pragma unroll
        for (int j = 0; j < 8; ++j) {
            float v = w[(kbase + j) * 64 + n];
            __bf16 hi = (__bf16)v;
            dst[idx * 8 + j] = hi;
            dst[4096 + idx * 8 + j] = (__bf16)(v - (float)hi);
        }
    }
}

// ---------------------------------------------------------------------------
// Gather aggregation: one wave per node, lane = dim. 12-wide unrolled chunk
// issues 12 independent row loads (vmcnt-overlapped) before any use; slots
// past deg are clamped to row 0 (L1-hot) and masked out of the sum.
// Optionally applies previous layer's BN affine + relu.
// ---------------------------------------------------------------------------
template <bool BN>
__global__ __launch_bounds__(256) void gather_kernel(
    const float* __restrict__ x, const float* __restrict__ sc,
    const int* __restrict__ deg, const int* __restrict__ esrc,
    float* __restrict__ agg)
{
    const int lane = threadIdx.x & 63;
    const int n = blockIdx.x * 4 + (threadIdx.x >> 6);
    if (n >= N_NODES) return;
    float scale = 1.0f, shift = 0.0f;
    if (BN) { scale = sc[lane]; shift = sc[64 + lane]; }
    const int d = min(deg[n], PAD);
    const int* ep = esrc + n * PAD;
    float sum = 0.0f;
    for (int j0 = 0; j0 < d; j0 += 12) {
        float v[12];
#pragma unroll
        for (int j = 0; j < 12; ++j) {
            unsigned s = (unsigned)ep[j0 + j];        // garbage past d -> clamp
            s = (s < (unsigned)N_NODES) ? s : 0u;
            v[j] = x[(size_t)s * 64 + lane];
        }
#pragma unroll
        for (int j = 0; j < 12; ++j) {
            float t = v[j];
            if (BN) t = fmaxf(fmaf(t, scale, shift), 0.0f);
            sum += (j0 + j < d) ? t : 0.0f;
        }
    }
    agg[(size_t)n * 64 + lane] = sum;
}

// ---------------------------------------------------------------------------
// Spill: the few deg>PAD edges, added atomically after gather.
// ---------------------------------------------------------------------------
template <bool BN>
__global__ __launch_bounds__(256) void spill_kernel(
    const float* __restrict__ x, const float* __restrict__ sc,
    const int* __restrict__ nspill, const int* __restrict__ spill,
    float* __restrict__ agg)
{
    const int lane = threadIdx.x & 63;
    const int w = blockIdx.x * 4 + (threadIdx.x >> 6);
    int ns = min(*nspill, SPILL_CAP);
    float scale = 1.0f, shift = 0.0f;
    if (BN) { scale = sc[lane]; shift = sc[64 + lane]; }
    for (int e = w; e < ns; e += 64) {               // 16 blocks * 4 waves
        int dst = spill[2 * e];
        int src = spill[2 * e + 1];
        float v = x[(size_t)src * 64 + lane];
        if (BN) v = fmaxf(fmaf(v, scale, shift), 0.0f);
        unsafeAtomicAdd(&agg[(size_t)dst * 64 + lane], v);
    }
}

// ---------------------------------------------------------------------------
// MFMA GIN MLP. Block = 4 waves; wave handles 16 nodes x all 64 output dims.
// h = (1+eps)*bn(x) + agg (agg read from h2buf, h2 written back in place).
// Each GEMM (K=64): fp32 split into bf16 hi/lo, 3 MFMA products.
// ---------------------------------------------------------------------------
template <bool BN>
__global__ __launch_bounds__(256) void mlp_mfma_kernel(
    const float* __restrict__ x, const float* __restrict__ sc,
    float* __restrict__ h2buf,
    const __bf16* __restrict__ wf1, const __bf16* __restrict__ wf2,
    const float* __restrict__ b1, const float* __restrict__ b2,
    const float* __restrict__ eps_all, int layer,
    float* __restrict__ sums)
{
    __shared__ __attribute__((aligned(16))) unsigned h1p[4][16][68];
    __shared__ float bnacc[128];

    const int tid = threadIdx.x;
    const int lane = tid & 63;
    const int wv = tid >> 6;
    const int q = lane >> 4;      // quad
    const int r = lane & 15;      // row-in-quad / col
    const int node0 = blockIdx.x * 64 + wv * 16;
    const bool active = node0 < N_NODES;

    if (tid < 128) bnacc[tid] = 0.0f;

    f32x4 acc[4];
    float bs[4], bq[4];
#pragma unroll
    for (int nt = 0; nt < 4; ++nt) {
        acc[nt] = (f32x4){0.f, 0.f, 0.f, 0.f};
        bs[nt] = 0.0f; bq[nt] = 0.0f;
    }

    if (active) {
        const float epsv = 1.0f + eps_all[layer];
#pragma unroll
        for (int kstep = 0; kstep < 2; ++kstep) {
            const int koff = kstep * 32 + q * 8;
            const float* xr = x + (size_t)(node0 + r) * 64 + koff;
            const float* ar = h2buf + (size_t)(node0 + r) * 64 + koff;
            float4 xa = *(const float4*)xr;
            float4 xb = *(const float4*)(xr + 4);
            float4 aa = *(const float4*)ar;
            float4 ab = *(const float4*)(ar + 4);
            float hv[8];
            const float* xap = (const float*)&xa;
            const float* xbp = (const float*)&xb;
            const float* aap = (const float*)&aa;
            const float* abp = (const float*)&ab;
            if (BN) {
                float4 s0 = *(const float4*)(sc + koff);
                float4 s1 = *(const float4*)(sc + koff + 4);
                float4 t0 = *(const float4*)(sc + 64 + koff);
                float4 t1 = *(const float4*)(sc + 64 + koff + 4);
                const float* s0p = (const float*)&s0;
                const float* s1p = (const float*)&s1;
                const float* t0p = (const float*)&t0;
                const float* t1p = (const float*)&t1;
#pragma unroll
                for (int j = 0; j < 4; ++j) {
                    float xv = fmaxf(fmaf(xap[j], s0p[j], t0p[j]), 0.0f);
                    hv[j] = fmaf(epsv, xv, aap[j]);
                    float xw = fmaxf(fmaf(xbp[j], s1p[j], t1p[j]), 0.0f);
                    hv[4 + j] = fmaf(epsv, xw, abp[j]);
                }
            } else {
#pragma unroll
                for (int j = 0; j < 4; ++j) {
                    hv[j] = fmaf(epsv, xap[j], aap[j]);
                    hv[4 + j] = fmaf(epsv, xbp[j], abp[j]);
                }
            }
            bf16x8 ahi, alo;
#pragma unroll
            for (int j = 0; j < 8; ++j) {
                __bf16 hi = (__bf16)hv[j];
                ahi[j] = hi;
                alo[j] = (__bf16)(hv[j] - (float)hi);
            }
#pragma unroll
            for (int nt = 0; nt < 4; ++nt) {
                const __bf16* bp = wf1 + ((kstep * 4 + nt) * 64 + lane) * 8;
                bf16x8 bhi = *(const bf16x8*)bp;
                bf16x8 blo = *(const bf16x8*)(bp + 4096);
                acc[nt] = __builtin_amdgcn_mfma_f32_16x16x32_bf16(ahi, bhi, acc[nt], 0, 0, 0);
                acc[nt] = __builtin_amdgcn_mfma_f32_16x16x32_bf16(alo, bhi, acc[nt], 0, 0, 0);
                acc[nt] = __builtin_amdgcn_mfma_f32_16x16x32_bf16(ahi, blo, acc[nt], 0, 0, 0);
            }
        }
#pragma unroll
        for (int nt = 0; nt < 4; ++nt) {
            float b1v = b1[nt * 16 + r];
#pragma unroll
            for (int reg = 0; reg < 4; ++reg) {
                float v = fmaxf(acc[nt][reg] + b1v, 0.0f);
                __bf16 hi = (__bf16)v;
                __bf16 lo = (__bf16)(v - (float)hi);
                unsigned pk = ((unsigned)__builtin_bit_cast(unsigned short, hi) << 16)
                            | (unsigned)__builtin_bit_cast(unsigned short, lo);
                h1p[wv][q * 4 + reg][nt * 16 + r] = pk;
            }
            acc[nt] = (f32x4){0.f, 0.f, 0.f, 0.f};
        }
    }
    __syncthreads();
    if (active) {
#pragma unroll
        for (int kstep = 0; kstep < 2; ++kstep) {
            uint4 p0 = *(const uint4*)&h1p[wv][r][kstep * 32 + q * 8];
            uint4 p1 = *(const uint4*)&h1p[wv][r][kstep * 32 + q * 8 + 4];
            unsigned pk[8] = {p0.x, p0.y, p0.z, p0.w, p1.x, p1.y, p1.z, p1.w};
            bf16x8 ahi, alo;
#pragma unroll
            for (int j = 0; j < 8; ++j) {
                ahi[j] = __builtin_bit_cast(__bf16, (unsigned short)(pk[j] >> 16));
                alo[j] = __builtin_bit_cast(__bf16, (unsigned short)(pk[j] & 0xffffu));
            }
#pragma unroll
            for (int nt = 0; nt < 4; ++nt) {
                const __bf16* bp = wf2 + ((kstep * 4 + nt) * 64 + lane) * 8;
                bf16x8 bhi = *(const bf16x8*)bp;
                bf16x8 blo = *(const bf16x8*)(bp + 4096);
                acc[nt] = __builtin_amdgcn_mfma_f32_16x16x32_bf16(ahi, bhi, acc[nt], 0, 0, 0);
                acc[nt] = __builtin_amdgcn_mfma_f32_16x16x32_bf16(alo, bhi, acc[nt], 0, 0, 0);
                acc[nt] = __builtin_amdgcn_mfma_f32_16x16x32_bf16(ahi, blo, acc[nt], 0, 0, 0);
            }
        }
#pragma unroll
        for (int nt = 0; nt < 4; ++nt) {
            float b2v = b2[nt * 16 + r];
#pragma unroll
            for (int reg = 0; reg < 4; ++reg) {
                float v = fmaxf(acc[nt][reg] + b2v, 0.0f);
                h2buf[(size_t)(node0 + q * 4 + reg) * 64 + nt * 16 + r] = v;
                bs[nt] += v;
                bq[nt] = fmaf(v, v, bq[nt]);
            }
        }
    }
#pragma unroll
    for (int nt = 0; nt < 4; ++nt) {
        float s = bs[nt];
        s += __shfl_xor(s, 16);
        s += __shfl_xor(s, 32);
        float ss = bq[nt];
        ss += __shfl_xor(ss, 16);
        ss += __shfl_xor(ss, 32);
        if (q == 0) {
            atomicAdd(&bnacc[nt * 16 + r], s);
            atomicAdd(&bnacc[64 + nt * 16 + r], ss);
        }
    }
    __syncthreads();
    if (tid < 128) unsafeAtomicAdd(&sums[tid], bnacc[tid]);
}

// ---------------------------------------------------------------------------
// Segmented global mean pool (batch sorted): register-accumulate per graph,
// one atomic flush per boundary. Applies last layer's BN affine+relu on load.
// ---------------------------------------------------------------------------
__global__ __launch_bounds__(256) void pool_kernel(
    const float* __restrict__ h2, const float* __restrict__ sc,
    const int* __restrict__ batch,
    float* __restrict__ pooled, float* __restrict__ counts)
{
    const int lane = threadIdx.x & 63;
    const int w = blockIdx.x * 4 + (threadIdx.x >> 6);
    const int nw = POOL_BLOCKS * 4;
    const int npw = (N_NODES + nw - 1) / nw;
    int n0 = w * npw;
    if (n0 >= N_NODES) return;
    int n1 = n0 + npw;
    if (n1 > N_NODES) n1 = N_NODES;

    const float scale = sc[lane];
    const float shift = sc[64 + lane];

    int cur = batch[n0];
    float acc = 0.0f, cnt = 0.0f;
    for (int n = n0; n < n1; ++n) {
        int g = batch[n];                       // wave-uniform
        if (g != cur) {
            unsafeAtomicAdd(&pooled[cur * 64 + lane], acc);
            if (lane == 0) unsafeAtomicAdd(&counts[cur], cnt);
            acc = 0.0f; cnt = 0.0f; cur = g;
        }
        float v = h2[(size_t)n * 64 + lane];
        v = fmaxf(fmaf(v, scale, shift), 0.0f);
        acc += v;
        cnt += 1.0f;
    }
    unsafeAtomicAdd(&pooled[cur * 64 + lane], acc);
    if (lane == 0) unsafeAtomicAdd(&counts[cur], cnt);
}

// ---------------------------------------------------------------------------
// Final linear.
// ---------------------------------------------------------------------------
__global__ __launch_bounds__(256) void final_kernel(
    const float* __restrict__ pooled, const float* __restrict__ counts,
    const float* __restrict__ lin_w, const float* __restrict__ lin_b,
    float* __restrict__ out)
{
    int t = blockIdx.x * 256 + threadIdx.x;
    if (t >= N_GRAPHS * OUT_DIM) return;
    int g = t / OUT_DIM;
    int o = t - g * OUT_DIM;
    float acc = 0.0f;
#pragma unroll 8
    for (int d = 0; d < 64; ++d)
        acc = fmaf(pooled[g * 64 + d], lin_w[d * OUT_DIM + o], acc);
    float c = fmaxf(counts[g], 1.0f);
    out[t] = acc / c + lin_b[o];
}

extern "C" void kernel_launch(void* const* d_in, const int* in_sizes, int n_in,
                              void* d_out, int out_size, void* d_ws, size_t ws_size,
                              hipStream_t stream)
{
    const float* x0    = (const float*)d_in[0];
    const int*   ei    = (const int*)d_in[1];
    const int*   batch = (const int*)d_in[2];
    const float* w1    = (const float*)d_in[3];
    const float* b1    = (const float*)d_in[4];
    const float* w2    = (const float*)d_in[5];
    const float* b2    = (const float*)d_in[6];
    const float* gamma = (const float*)d_in[7];
    const float* beta  = (const float*)d_in[8];
    const float* eps_g = (const float*)d_in[9];
    const float* lin_w = (const float*)d_in[10];
    const float* lin_b = (const float*)d_in[11];
    float* out = (float*)d_out;

    // Workspace layout.
    float* ws   = (float*)d_ws;
    float* A    = ws;                                // ping, 6.4M floats
    float* B    = ws + (size_t)N_NODES * 64;         // pong, 6.4M floats
    float* SUMS = ws + (size_t)2 * N_NODES * 64;     // 3*128 (zeroed once)
    float* POOL = SUMS + 384;                        // 16384 (zeroed once)
    float* CNT  = POOL + N_GRAPHS * 64;              // 256   (zeroed once)
    float* SC   = CNT + N_GRAPHS;                    // 3*128
    __bf16* WF  = (__bf16*)(SC + 384);               // 6*8192 bf16 = 96 KB
    int*   DEG    = (int*)(WF + 6 * 8192);           // 100000 (zeroed once)
    int*   NSPILL = DEG + N_NODES;                   // 16    (zeroed once)
    int*   SPILL  = NSPILL + 16;                     // 2*SPILL_CAP
    int*   ESRC   = SPILL + 2 * SPILL_CAP;           // 24*N = 9.6 MB

    const int edge_blocks = (N_EDGES + 255) / 256;    // 3907
    const int node_wave_blocks = (N_NODES + 3) / 4;   // 25000

    // ---- once per call: zeroing, weight fragments, edge fill ----
    hipMemsetAsync(DEG, 0, (N_NODES + 16) * sizeof(int), stream);
    hipMemsetAsync(SUMS, 0, (384 + N_GRAPHS * 64 + N_GRAPHS) * sizeof(float), stream);
    wprep_kernel<<<6, 256, 0, stream>>>(w1, w2, WF);
    fill_kernel<<<edge_blocks, 256, 0, stream>>>(ei, DEG, ESRC, NSPILL, SPILL);

    // ---- 3 GIN layers (BN of layer L fused into consumers of layer L+1) ----
    // L0: x0 -> agg in A -> h2_0 in A
    gather_kernel<false><<<node_wave_blocks, 256, 0, stream>>>(
        x0, nullptr, DEG, ESRC, A);
    spill_kernel<false><<<16, 256, 0, stream>>>(x0, nullptr, NSPILL, SPILL, A);
    mlp_mfma_kernel<false><<<MLP_BLOCKS, 256, 0, stream>>>(
        x0, nullptr, A, WF, WF + 8192, b1, b2, eps_g, 0, SUMS);
    bnprep_kernel<<<1, 64, 0, stream>>>(SUMS, gamma, beta, SC);

    // L1: bn(A) -> agg in B -> h2_1 in B
    gather_kernel<true><<<node_wave_blocks, 256, 0, stream>>>(
        A, SC, DEG, ESRC, B);
    spill_kernel<true><<<16, 256, 0, stream>>>(A, SC, NSPILL, SPILL, B);
    mlp_mfma_kernel<true><<<MLP_BLOCKS, 256, 0, stream>>>(
        A, SC, B, WF + 16384, WF + 24576, b1 + 64, b2 + 64, eps_g, 1, SUMS + 128);
    bnprep_kernel<<<1, 64, 0, stream>>>(SUMS + 128, gamma + 64, beta + 64, SC + 128);

    // L2: bn(B) -> agg in A -> h2_2 in A
    gather_kernel<true><<<node_wave_blocks, 256, 0, stream>>>(
        B, SC + 128, DEG, ESRC, A);
    spill_kernel<true><<<16, 256, 0, stream>>>(B, SC + 128, NSPILL, SPILL, A);
    mlp_mfma_kernel<true><<<MLP_BLOCKS, 256, 0, stream>>>(
        B, SC + 128, A, WF + 32768, WF + 40960, b1 + 128, b2 + 128, eps_g, 2, SUMS + 256);
    bnprep_kernel<<<1, 64, 0, stream>>>(SUMS + 256, gamma + 128, beta + 128, SC + 256);

    // ---- segmented pool (applies bn of L2) + linear ----
    pool_kernel<<<POOL_BLOCKS, 256, 0, stream>>>(A, SC + 256, batch, POOL, CNT);
    final_kernel<<<(N_GRAPHS * OUT_DIM + 255) / 256, 256, 0, stream>>>(
        POOL, CNT, lin_w, lin_b, out);
}

// Round 7
// 442.501 us; speedup vs baseline: 3.5736x; 1.0557x over previous
//
#include <hip/hip_runtime.h>
#include <hip/hip_bf16.h>

#define N_NODES 100000
#define N_EDGES 1000000
#define DIM 64
#define N_GRAPHS 256
#define OUT_DIM 10
#define BN_EPS 1e-5f

#define POOL_BLOCKS 512                      // 2048 waves
#define MLP_BLOCKS ((N_NODES + 63) / 64)     // 1563
#define PAD 24                               // slots per node; P(deg>24)~4e-5
#define SPILL_CAP 8192
#define NPART 8                              // dst partitions (one per XCD)
#define PART_SZ ((N_NODES + NPART - 1) / NPART)   // 12500

typedef __bf16 bf16x8 __attribute__((ext_vector_type(8)));
typedef float f32x4 __attribute__((ext_vector_type(4)));

// ---------------------------------------------------------------------------
// Edge fill, XCD-partitioned: 8 block-replicas per 256-edge tile; replica
// part = blockIdx&7 (round-robin blockIdx->XCD heuristic) handles only edges
// whose dst is in [part*12500, (part+1)*12500). Each 1.2 MB ESRC range (and
// its deg counters) is then written by one XCD's L2 only -> dirty lines
// accumulate ~7 writes before a single writeback (kills the 8-XCD dirty-copy
// duplication measured as 61 MB WRITE_SIZE in R5). Heuristic is locality-only:
// correctness holds under any block->XCD mapping.
// ---------------------------------------------------------------------------
__global__ __launch_bounds__(256) void fill_kernel(
    const int* __restrict__ ei, int* __restrict__ deg,
    int* __restrict__ esrc, int* __restrict__ nspill, int* __restrict__ spill)
{
    const int part = blockIdx.x & (NPART - 1);
    const int e = (blockIdx.x >> 3) * 256 + threadIdx.x;
    if (e >= N_EDGES) return;
    int dst = ei[N_EDGES + e];
    int lo = part * PART_SZ;
    if (dst < lo || dst >= lo + PART_SZ) return;
    int src = ei[e];
    int pos = atomicAdd(&deg[dst], 1);
    if (pos < PAD) {
        esrc[dst * PAD + pos] = src;
    } else {
        int sp = atomicAdd(nspill, 1);
        if (sp < SPILL_CAP) { spill[2 * sp] = dst; spill[2 * sp + 1] = src; }
    }
}

// ---------------------------------------------------------------------------
// BN prep: per-dim affine from accumulated sum/sumsq.
// sc[0..63] = scale, sc[64..127] = shift.  y = relu(scale*v + shift)
// ---------------------------------------------------------------------------
__global__ __launch_bounds__(64) void bnprep_kernel(
    const float* __restrict__ sums, const float* __restrict__ gamma,
    const float* __restrict__ beta, float* __restrict__ sc)
{
    int d = threadIdx.x;
    const float inv_n = 1.0f / (float)N_NODES;
    float mean = sums[d] * inv_n;
    float m2 = sums[64 + d] * inv_n;
    float var = m2 - mean * mean;
    float scale = gamma[d] * rsqrtf(var + BN_EPS);
    sc[d] = scale;
    sc[64 + d] = fmaf(-mean, scale, beta[d]);
}

// ---------------------------------------------------------------------------
// Weight prep: split each 64x64 fp32 W into bf16 hi/lo, stored in MFMA
// B-fragment order: blob[(kstep*4+ntile)*64 + lane][j]; hi at +0, lo at +4096.
// ---------------------------------------------------------------------------
__global__ __launch_bounds__(256) void wprep_kernel(
    const float* __restrict__ w1, const float* __restrict__ w2,
    __bf16* __restrict__ wf)
{
    int L = blockIdx.x >> 1, mat = blockIdx.x & 1;
    const float* w = (mat ? w2 : w1) + L * 4096;
    __bf16* dst = wf + blockIdx.x * 8192;
#pragma unroll
    for (int r = 0; r < 2; ++r) {
        int idx = threadIdx.x + 256 * r;          // (kstep*4+nt)*64 + lane
        int lane = idx & 63;
        int kt = idx >> 6;
        int kstep = kt >> 2, nt = kt & 3;
        int n = nt * 16 + (lane & 15);
        int kbase = kstep * 32 + (lane >> 4) * 8;
#pragma unroll
        for (int j = 0; j < 8; ++j) {
            float v = w[(kbase + j) * 64 + n];
            __bf16 hi = (__bf16)v;
            dst[idx * 8 + j] = hi;
            dst[4096 + idx * 8 + j] = (__bf16)(v - (float)hi);
        }
    }
}

// ---------------------------------------------------------------------------
// Gather aggregation: one wave per node, lane = dim. 12-wide unrolled chunk
// issues 12 independent row loads (vmcnt-overlapped) before any use; slots
// past deg are clamped to row 0 (L1-hot) and masked out of the sum.
// Optionally applies previous layer's BN affine + relu.
// ---------------------------------------------------------------------------
template <bool BN>
__global__ __launch_bounds__(256) void gather_kernel(
    const float* __restrict__ x, const float* __restrict__ sc,
    const int* __restrict__ deg, const int* __restrict__ esrc,
    float* __restrict__ agg)
{
    const int lane = threadIdx.x & 63;
    const int n = blockIdx.x * 4 + (threadIdx.x >> 6);
    if (n >= N_NODES) return;
    float scale = 1.0f, shift = 0.0f;
    if (BN) { scale = sc[lane]; shift = sc[64 + lane]; }
    const int d = min(deg[n], PAD);
    const int* ep = esrc + n * PAD;
    float sum = 0.0f;
    for (int j0 = 0; j0 < d; j0 += 12) {
        float v[12];
#pragma unroll
        for (int j = 0; j < 12; ++j) {
            unsigned s = (unsigned)ep[j0 + j];        // garbage past d -> clamp
            s = (s < (unsigned)N_NODES) ? s : 0u;
            v[j] = x[(size_t)s * 64 + lane];
        }
#pragma unroll
        for (int j = 0; j < 12; ++j) {
            float t = v[j];
            if (BN) t = fmaxf(fmaf(t, scale, shift), 0.0f);
            sum += (j0 + j < d) ? t : 0.0f;
        }
    }
    agg[(size_t)n * 64 + lane] = sum;
}

// ---------------------------------------------------------------------------
// Spill: the few deg>PAD edges, added atomically after gather.
// ---------------------------------------------------------------------------
template <bool BN>
__global__ __launch_bounds__(256) void spill_kernel(
    const float* __restrict__ x, const float* __restrict__ sc,
    const int* __restrict__ nspill, const int* __restrict__ spill,
    float* __restrict__ agg)
{
    const int lane = threadIdx.x & 63;
    const int w = blockIdx.x * 4 + (threadIdx.x >> 6);
    int ns = min(*nspill, SPILL_CAP);
    float scale = 1.0f, shift = 0.0f;
    if (BN) { scale = sc[lane]; shift = sc[64 + lane]; }
    for (int e = w; e < ns; e += 64) {               // 16 blocks * 4 waves
        int dst = spill[2 * e];
        int src = spill[2 * e + 1];
        float v = x[(size_t)src * 64 + lane];
        if (BN) v = fmaxf(fmaf(v, scale, shift), 0.0f);
        unsafeAtomicAdd(&agg[(size_t)dst * 64 + lane], v);
    }
}

// ---------------------------------------------------------------------------
// MFMA GIN MLP. Block = 4 waves; wave handles 16 nodes x all 64 output dims.
// h = (1+eps)*bn(x) + agg (agg read from h2buf, h2 written back in place).
// Each GEMM (K=64): fp32 split into bf16 hi/lo, 3 MFMA products.
// ---------------------------------------------------------------------------
template <bool BN>
__global__ __launch_bounds__(256) void mlp_mfma_kernel(
    const float* __restrict__ x, const float* __restrict__ sc,
    float* __restrict__ h2buf,
    const __bf16* __restrict__ wf1, const __bf16* __restrict__ wf2,
    const float* __restrict__ b1, const float* __restrict__ b2,
    const float* __restrict__ eps_all, int layer,
    float* __restrict__ sums)
{
    __shared__ __attribute__((aligned(16))) unsigned h1p[4][16][68];
    __shared__ float bnacc[128];

    const int tid = threadIdx.x;
    const int lane = tid & 63;
    const int wv = tid >> 6;
    const int q = lane >> 4;      // quad
    const int r = lane & 15;      // row-in-quad / col
    const int node0 = blockIdx.x * 64 + wv * 16;
    const bool active = node0 < N_NODES;

    if (tid < 128) bnacc[tid] = 0.0f;

    f32x4 acc[4];
    float bs[4], bq[4];
#pragma unroll
    for (int nt = 0; nt < 4; ++nt) {
        acc[nt] = (f32x4){0.f, 0.f, 0.f, 0.f};
        bs[nt] = 0.0f; bq[nt] = 0.0f;
    }

    if (active) {
        const float epsv = 1.0f + eps_all[layer];
#pragma unroll
        for (int kstep = 0; kstep < 2; ++kstep) {
            const int koff = kstep * 32 + q * 8;
            const float* xr = x + (size_t)(node0 + r) * 64 + koff;
            const float* ar = h2buf + (size_t)(node0 + r) * 64 + koff;
            float4 xa = *(const float4*)xr;
            float4 xb = *(const float4*)(xr + 4);
            float4 aa = *(const float4*)ar;
            float4 ab = *(const float4*)(ar + 4);
            float hv[8];
            const float* xap = (const float*)&xa;
            const float* xbp = (const float*)&xb;
            const float* aap = (const float*)&aa;
            const float* abp = (const float*)&ab;
            if (BN) {
                float4 s0 = *(const float4*)(sc + koff);
                float4 s1 = *(const float4*)(sc + koff + 4);
                float4 t0 = *(const float4*)(sc + 64 + koff);
                float4 t1 = *(const float4*)(sc + 64 + koff + 4);
                const float* s0p = (const float*)&s0;
                const float* s1p = (const float*)&s1;
                const float* t0p = (const float*)&t0;
                const float* t1p = (const float*)&t1;
#pragma unroll
                for (int j = 0; j < 4; ++j) {
                    float xv = fmaxf(fmaf(xap[j], s0p[j], t0p[j]), 0.0f);
                    hv[j] = fmaf(epsv, xv, aap[j]);
                    float xw = fmaxf(fmaf(xbp[j], s1p[j], t1p[j]), 0.0f);
                    hv[4 + j] = fmaf(epsv, xw, abp[j]);
                }
            } else {
#pragma unroll
                for (int j = 0; j < 4; ++j) {
                    hv[j] = fmaf(epsv, xap[j], aap[j]);
                    hv[4 + j] = fmaf(epsv, xbp[j], abp[j]);
                }
            }
            bf16x8 ahi, alo;
#pragma unroll
            for (int j = 0; j < 8; ++j) {
                __bf16 hi = (__bf16)hv[j];
                ahi[j] = hi;
                alo[j] = (__bf16)(hv[j] - (float)hi);
            }
#pragma unroll
            for (int nt = 0; nt < 4; ++nt) {
                const __bf16* bp = wf1 + ((kstep * 4 + nt) * 64 + lane) * 8;
                bf16x8 bhi = *(const bf16x8*)bp;
                bf16x8 blo = *(const bf16x8*)(bp + 4096);
                acc[nt] = __builtin_amdgcn_mfma_f32_16x16x32_bf16(ahi, bhi, acc[nt], 0, 0, 0);
                acc[nt] = __builtin_amdgcn_mfma_f32_16x16x32_bf16(alo, bhi, acc[nt], 0, 0, 0);
                acc[nt] = __builtin_amdgcn_mfma_f32_16x16x32_bf16(ahi, blo, acc[nt], 0, 0, 0);
            }
        }
#pragma unroll
        for (int nt = 0; nt < 4; ++nt) {
            float b1v = b1[nt * 16 + r];
#pragma unroll
            for (int reg = 0; reg < 4; ++reg) {
                float v = fmaxf(acc[nt][reg] + b1v, 0.0f);
                __bf16 hi = (__bf16)v;
                __bf16 lo = (__bf16)(v - (float)hi);
                unsigned pk = ((unsigned)__builtin_bit_cast(unsigned short, hi) << 16)
                            | (unsigned)__builtin_bit_cast(unsigned short, lo);
                h1p[wv][q * 4 + reg][nt * 16 + r] = pk;
            }
            acc[nt] = (f32x4){0.f, 0.f, 0.f, 0.f};
        }
    }
    __syncthreads();
    if (active) {
#pragma unroll
        for (int kstep = 0; kstep < 2; ++kstep) {
            uint4 p0 = *(const uint4*)&h1p[wv][r][kstep * 32 + q * 8];
            uint4 p1 = *(const uint4*)&h1p[wv][r][kstep * 32 + q * 8 + 4];
            unsigned pk[8] = {p0.x, p0.y, p0.z, p0.w, p1.x, p1.y, p1.z, p1.w};
            bf16x8 ahi, alo;
#pragma unroll
            for (int j = 0; j < 8; ++j) {
                ahi[j] = __builtin_bit_cast(__bf16, (unsigned short)(pk[j] >> 16));
                alo[j] = __builtin_bit_cast(__bf16, (unsigned short)(pk[j] & 0xffffu));
            }
#pragma unroll
            for (int nt = 0; nt < 4; ++nt) {
                const __bf16* bp = wf2 + ((kstep * 4 + nt) * 64 + lane) * 8;
                bf16x8 bhi = *(const bf16x8*)bp;
                bf16x8 blo = *(const bf16x8*)(bp + 4096);
                acc[nt] = __builtin_amdgcn_mfma_f32_16x16x32_bf16(ahi, bhi, acc[nt], 0, 0, 0);
                acc[nt] = __builtin_amdgcn_mfma_f32_16x16x32_bf16(alo, bhi, acc[nt], 0, 0, 0);
                acc[nt] = __builtin_amdgcn_mfma_f32_16x16x32_bf16(ahi, blo, acc[nt], 0, 0, 0);
            }
        }
#pragma unroll
        for (int nt = 0; nt < 4; ++nt) {
            float b2v = b2[nt * 16 + r];
#pragma unroll
            for (int reg = 0; reg < 4; ++reg) {
                float v = fmaxf(acc[nt][reg] + b2v, 0.0f);
                h2buf[(size_t)(node0 + q * 4 + reg) * 64 + nt * 16 + r] = v;
                bs[nt] += v;
                bq[nt] = fmaf(v, v, bq[nt]);
            }
        }
    }
#pragma unroll
    for (int nt = 0; nt < 4; ++nt) {
        float s = bs[nt];
        s += __shfl_xor(s, 16);
        s += __shfl_xor(s, 32);
        float ss = bq[nt];
        ss += __shfl_xor(ss, 16);
        ss += __shfl_xor(ss, 32);
        if (q == 0) {
            atomicAdd(&bnacc[nt * 16 + r], s);
            atomicAdd(&bnacc[64 + nt * 16 + r], ss);
        }
    }
    __syncthreads();
    if (tid < 128) unsafeAtomicAdd(&sums[tid], bnacc[tid]);
}

// ---------------------------------------------------------------------------
// Segmented global mean pool (batch sorted): register-accumulate per graph,
// one atomic flush per boundary. Applies last layer's BN affine+relu on load.
// ---------------------------------------------------------------------------
__global__ __launch_bounds__(256) void pool_kernel(
    const float* __restrict__ h2, const float* __restrict__ sc,
    const int* __restrict__ batch,
    float* __restrict__ pooled, float* __restrict__ counts)
{
    const int lane = threadIdx.x & 63;
    const int w = blockIdx.x * 4 + (threadIdx.x >> 6);
    const int nw = POOL_BLOCKS * 4;
    const int npw = (N_NODES + nw - 1) / nw;
    int n0 = w * npw;
    if (n0 >= N_NODES) return;
    int n1 = n0 + npw;
    if (n1 > N_NODES) n1 = N_NODES;

    const float scale = sc[lane];
    const float shift = sc[64 + lane];

    int cur = batch[n0];
    float acc = 0.0f, cnt = 0.0f;
    for (int n = n0; n < n1; ++n) {
        int g = batch[n];                       // wave-uniform
        if (g != cur) {
            unsafeAtomicAdd(&pooled[cur * 64 + lane], acc);
            if (lane == 0) unsafeAtomicAdd(&counts[cur], cnt);
            acc = 0.0f; cnt = 0.0f; cur = g;
        }
        float v = h2[(size_t)n * 64 + lane];
        v = fmaxf(fmaf(v, scale, shift), 0.0f);
        acc += v;
        cnt += 1.0f;
    }
    unsafeAtomicAdd(&pooled[cur * 64 + lane], acc);
    if (lane == 0) unsafeAtomicAdd(&counts[cur], cnt);
}

// ---------------------------------------------------------------------------
// Final linear.
// ---------------------------------------------------------------------------
__global__ __launch_bounds__(256) void final_kernel(
    const float* __restrict__ pooled, const float* __restrict__ counts,
    const float* __restrict__ lin_w, const float* __restrict__ lin_b,
    float* __restrict__ out)
{
    int t = blockIdx.x * 256 + threadIdx.x;
    if (t >= N_GRAPHS * OUT_DIM) return;
    int g = t / OUT_DIM;
    int o = t - g * OUT_DIM;
    float acc = 0.0f;
#pragma unroll 8
    for (int d = 0; d < 64; ++d)
        acc = fmaf(pooled[g * 64 + d], lin_w[d * OUT_DIM + o], acc);
    float c = fmaxf(counts[g], 1.0f);
    out[t] = acc / c + lin_b[o];
}

extern "C" void kernel_launch(void* const* d_in, const int* in_sizes, int n_in,
                              void* d_out, int out_size, void* d_ws, size_t ws_size,
                              hipStream_t stream)
{
    const float* x0    = (const float*)d_in[0];
    const int*   ei    = (const int*)d_in[1];
    const int*   batch = (const int*)d_in[2];
    const float* w1    = (const float*)d_in[3];
    const float* b1    = (const float*)d_in[4];
    const float* w2    = (const float*)d_in[5];
    const float* b2    = (const float*)d_in[6];
    const float* gamma = (const float*)d_in[7];
    const float* beta  = (const float*)d_in[8];
    const float* eps_g = (const float*)d_in[9];
    const float* lin_w = (const float*)d_in[10];
    const float* lin_b = (const float*)d_in[11];
    float* out = (float*)d_out;

    // Workspace layout: everything that must start at 0 is contiguous
    // (SUMS..NSPILL) -> single memset.
    float* ws   = (float*)d_ws;
    float* A    = ws;                                // ping, 6.4M floats
    float* B    = ws + (size_t)N_NODES * 64;         // pong, 6.4M floats
    float* SUMS = ws + (size_t)2 * N_NODES * 64;     // 3*128   [zeroed]
    float* POOL = SUMS + 384;                        // 16384   [zeroed]
    float* CNT  = POOL + N_GRAPHS * 64;              // 256     [zeroed]
    int*   DEG    = (int*)(CNT + N_GRAPHS);          // 100000  [zeroed]
    int*   NSPILL = DEG + N_NODES;                   // 16      [zeroed]
    float* SC   = (float*)(NSPILL + 16);             // 3*128
    __bf16* WF  = (__bf16*)(SC + 384);               // 6*8192 bf16 = 96 KB
    int*   SPILL  = (int*)(WF + 6 * 8192);           // 2*SPILL_CAP
    int*   ESRC   = SPILL + 2 * SPILL_CAP;           // 24*N = 9.6 MB

    const size_t zero_bytes = (384 + N_GRAPHS * 64 + N_GRAPHS) * sizeof(float)
                            + (N_NODES + 16) * sizeof(int);
    const int fill_blocks = ((N_EDGES + 255) / 256) * NPART;  // 31256
    const int node_wave_blocks = (N_NODES + 3) / 4;           // 25000

    // ---- once per call: zeroing, weight fragments, edge fill ----
    hipMemsetAsync(SUMS, 0, zero_bytes, stream);
    wprep_kernel<<<6, 256, 0, stream>>>(w1, w2, WF);
    fill_kernel<<<fill_blocks, 256, 0, stream>>>(ei, DEG, ESRC, NSPILL, SPILL);

    // ---- 3 GIN layers (BN of layer L fused into consumers of layer L+1) ----
    // L0: x0 -> agg in A -> h2_0 in A
    gather_kernel<false><<<node_wave_blocks, 256, 0, stream>>>(
        x0, nullptr, DEG, ESRC, A);
    spill_kernel<false><<<16, 256, 0, stream>>>(x0, nullptr, NSPILL, SPILL, A);
    mlp_mfma_kernel<false><<<MLP_BLOCKS, 256, 0, stream>>>(
        x0, nullptr, A, WF, WF + 8192, b1, b2, eps_g, 0, SUMS);
    bnprep_kernel<<<1, 64, 0, stream>>>(SUMS, gamma, beta, SC);

    // L1: bn(A) -> agg in B -> h2_1 in B
    gather_kernel<true><<<node_wave_blocks, 256, 0, stream>>>(
        A, SC, DEG, ESRC, B);
    spill_kernel<true><<<16, 256, 0, stream>>>(A, SC, NSPILL, SPILL, B);
    mlp_mfma_kernel<true><<<MLP_BLOCKS, 256, 0, stream>>>(
        A, SC, B, WF + 16384, WF + 24576, b1 + 64, b2 + 64, eps_g, 1, SUMS + 128);
    bnprep_kernel<<<1, 64, 0, stream>>>(SUMS + 128, gamma + 64, beta + 64, SC + 128);

    // L2: bn(B) -> agg in A -> h2_2 in A
    gather_kernel<true><<<node_wave_blocks, 256, 0, stream>>>(
        B, SC + 128, DEG, ESRC, A);
    spill_kernel<true><<<16, 256, 0, stream>>>(B, SC + 128, NSPILL, SPILL, A);
    mlp_mfma_kernel<true><<<MLP_BLOCKS, 256, 0, stream>>>(
        B, SC + 128, A, WF + 32768, WF + 40960, b1 + 128, b2 + 128, eps_g, 2, SUMS + 256);
    bnprep_kernel<<<1, 64, 0, stream>>>(SUMS + 256, gamma + 128, beta + 128, SC + 256);

    // ---- segmented pool (applies bn of L2) + linear ----
    pool_kernel<<<POOL_BLOCKS, 256, 0, stream>>>(A, SC + 256, batch, POOL, CNT);
    final_kernel<<<(N_GRAPHS * OUT_DIM + 255) / 256, 256, 0, stream>>>(
        POOL, CNT, lin_w, lin_b, out);
}

// Round 8
// 418.361 us; speedup vs baseline: 3.7798x; 1.0577x over previous
//
#include <hip/hip_runtime.h>
#include <hip/hip_bf16.h>

#define N_NODES 100000
#define N_EDGES 1000000
#define DIM 64
#define N_GRAPHS 256
#define OUT_DIM 10
#define BN_EPS 1e-5f

#define POOL_BLOCKS 512                      // 2048 waves
#define LAYER_BLOCKS ((N_NODES + 63) / 64)   // 1563
#define PAD 24                               // slots per node; P(deg>24)~4e-5
#define SPILL_CAP 8192
#define NPART 8                              // dst partitions (one per XCD)
#define PART_SZ ((N_NODES + NPART - 1) / NPART)   // 12500

typedef __bf16 bf16x8 __attribute__((ext_vector_type(8)));
typedef float f32x4 __attribute__((ext_vector_type(4)));

// ---------------------------------------------------------------------------
// Edge fill, XCD-partitioned (see R6): 8 block-replicas per 256-edge tile;
// replica part=blockIdx&7 handles only dst in its 12500-node range so each
// ESRC range is written by ~one XCD's L2 (kills cross-XCD dirty-line dup).
// ---------------------------------------------------------------------------
__global__ __launch_bounds__(256) void fill_kernel(
    const int* __restrict__ ei, int* __restrict__ deg,
    int* __restrict__ esrc, int* __restrict__ nspill, int* __restrict__ spill)
{
    const int part = blockIdx.x & (NPART - 1);
    const int e = (blockIdx.x >> 3) * 256 + threadIdx.x;
    if (e >= N_EDGES) return;
    int dst = ei[N_EDGES + e];
    int lo = part * PART_SZ;
    if (dst < lo || dst >= lo + PART_SZ) return;
    int src = ei[e];
    int pos = atomicAdd(&deg[dst], 1);
    if (pos < PAD) {
        esrc[dst * PAD + pos] = src;
    } else {
        int sp = atomicAdd(nspill, 1);
        if (sp < SPILL_CAP) { spill[2 * sp] = dst; spill[2 * sp + 1] = src; }
    }
}

// ---------------------------------------------------------------------------
// BN prep: per-dim affine from accumulated sum/sumsq.
// sc[0..63] = scale, sc[64..127] = shift.  y = relu(scale*v + shift)
// ---------------------------------------------------------------------------
__global__ __launch_bounds__(64) void bnprep_kernel(
    const float* __restrict__ sums, const float* __restrict__ gamma,
    const float* __restrict__ beta, float* __restrict__ sc)
{
    int d = threadIdx.x;
    const float inv_n = 1.0f / (float)N_NODES;
    float mean = sums[d] * inv_n;
    float m2 = sums[64 + d] * inv_n;
    float var = m2 - mean * mean;
    float scale = gamma[d] * rsqrtf(var + BN_EPS);
    sc[d] = scale;
    sc[64 + d] = fmaf(-mean, scale, beta[d]);
}

// ---------------------------------------------------------------------------
// Weight prep: split each 64x64 fp32 W into bf16 hi/lo, stored in MFMA
// B-fragment order: blob[(kstep*4+ntile)*64 + lane][j]; hi at +0, lo at +4096.
// ---------------------------------------------------------------------------
__global__ __launch_bounds__(256) void wprep_kernel(
    const float* __restrict__ w1, const float* __restrict__ w2,
    __bf16* __restrict__ wf)
{
    int L = blockIdx.x >> 1, mat = blockIdx.x & 1;
    const float* w = (mat ? w2 : w1) + L * 4096;
    __bf16* dst = wf + blockIdx.x * 8192;
#pragma unroll
    for (int r = 0; r < 2; ++r) {
        int idx = threadIdx.x + 256 * r;          // (kstep*4+nt)*64 + lane
        int lane = idx & 63;
        int kt = idx >> 6;
        int kstep = kt >> 2, nt = kt & 3;
        int n = nt * 16 + (lane & 15);
        int kbase = kstep * 32 + (lane >> 4) * 8;
#pragma unroll
        for (int j = 0; j < 8; ++j) {
            float v = w[(kbase + j) * 64 + n];
            __bf16 hi = (__bf16)v;
            dst[idx * 8 + j] = hi;
            dst[4096 + idx * 8 + j] = (__bf16)(v - (float)hi);
        }
    }
}

// ---------------------------------------------------------------------------
// FUSED GIN layer: gather + spill + (1+eps)*self + 2-GEMM MLP + BN partials.
// Block = 4 waves, wave = 16 nodes. Phase A (lane=dim): h = (1+eps)*bn(x[n])
// + sum bn(x[src]) with 12-wide ILP loads; rare deg>PAD nodes scan the tiny
// spill list. h packed hi|lo bf16 into a per-wave LDS tile (A-frag layout,
// stride 68). Phase B: GEMM1 from LDS, h1 repack, GEMM2, epilogue.
// Per-wave LDS tiles -> NO mid-kernel barrier; gather-phase waves and
// MFMA-phase waves co-schedule on the CU (VMEM and MFMA pipes overlap).
// fp32 fidelity via bf16 hi/lo split, 3 MFMA products per tile.
// ---------------------------------------------------------------------------
template <bool BN>
__global__ __launch_bounds__(256) void layer_kernel(
    const float* __restrict__ x, const float* __restrict__ sc,
    const int* __restrict__ deg, const int* __restrict__ esrc,
    const int* __restrict__ nspill, const int* __restrict__ spill,
    float* __restrict__ h2out,
    const __bf16* __restrict__ wf1, const __bf16* __restrict__ wf2,
    const float* __restrict__ b1, const float* __restrict__ b2,
    const float* __restrict__ eps_all, int layer,
    float* __restrict__ sums)
{
    __shared__ __attribute__((aligned(16))) unsigned hbuf[4][16][68];
    __shared__ __attribute__((aligned(16))) unsigned h1p[4][16][68];
    __shared__ float bnacc[128];

    const int tid = threadIdx.x;
    const int lane = tid & 63;
    const int wv = tid >> 6;
    const int q = lane >> 4;      // quad
    const int r = lane & 15;      // row-in-quad / col
    const int node0 = blockIdx.x * 64 + wv * 16;
    const bool active = node0 < N_NODES;   // 16-node tiles never straddle N

    if (tid < 128) bnacc[tid] = 0.0f;

    f32x4 acc[4];
    float bs[4], bq[4];
#pragma unroll
    for (int nt = 0; nt < 4; ++nt) {
        acc[nt] = (f32x4){0.f, 0.f, 0.f, 0.f};
        bs[nt] = 0.0f; bq[nt] = 0.0f;
    }

    float scale = 1.0f, shift = 0.0f;
    if (BN) { scale = sc[lane]; shift = sc[64 + lane]; }

    if (active) {
        const float epsv = 1.0f + eps_all[layer];
        // ---- Phase A: gather + self, lane = dim ----
        for (int i = 0; i < 16; ++i) {
            const int n = node0 + i;
            float xv = x[(size_t)n * 64 + lane];
            if (BN) xv = fmaxf(fmaf(xv, scale, shift), 0.0f);
            float hval = epsv * xv;
            const int dfull = deg[n];
            const int d = min(dfull, PAD);
            const int* ep = esrc + (size_t)n * PAD;
            for (int j0 = 0; j0 < d; j0 += 12) {
                float v[12];
#pragma unroll
                for (int j = 0; j < 12; ++j) {
                    unsigned s = (unsigned)ep[j0 + j];   // garbage past d -> clamp
                    s = (s < (unsigned)N_NODES) ? s : 0u;
                    v[j] = x[(size_t)s * 64 + lane];
                }
#pragma unroll
                for (int j = 0; j < 12; ++j) {
                    float t = v[j];
                    if (BN) t = fmaxf(fmaf(t, scale, shift), 0.0f);
                    hval += (j0 + j < d) ? t : 0.0f;
                }
            }
            if (dfull > PAD) {                  // rare: scan tiny spill list
                int ns = min(*nspill, SPILL_CAP);
                for (int e = 0; e < ns; ++e) {
                    if (spill[2 * e] == n) {
                        float t = x[(size_t)spill[2 * e + 1] * 64 + lane];
                        if (BN) t = fmaxf(fmaf(t, scale, shift), 0.0f);
                        hval += t;
                    }
                }
            }
            __bf16 hi = (__bf16)hval;
            __bf16 lo = (__bf16)(hval - (float)hi);
            hbuf[wv][i][lane] = ((unsigned)__builtin_bit_cast(unsigned short, hi) << 16)
                              | (unsigned)__builtin_bit_cast(unsigned short, lo);
        }

        // ---- Phase B1: GEMM1 from LDS (per-wave tile, no barrier needed) ----
#pragma unroll
        for (int kstep = 0; kstep < 2; ++kstep) {
            uint4 p0 = *(const uint4*)&hbuf[wv][r][kstep * 32 + q * 8];
            uint4 p1 = *(const uint4*)&hbuf[wv][r][kstep * 32 + q * 8 + 4];
            unsigned pk[8] = {p0.x, p0.y, p0.z, p0.w, p1.x, p1.y, p1.z, p1.w};
            bf16x8 ahi, alo;
#pragma unroll
            for (int j = 0; j < 8; ++j) {
                ahi[j] = __builtin_bit_cast(__bf16, (unsigned short)(pk[j] >> 16));
                alo[j] = __builtin_bit_cast(__bf16, (unsigned short)(pk[j] & 0xffffu));
            }
#pragma unroll
            for (int nt = 0; nt < 4; ++nt) {
                const __bf16* bp = wf1 + ((kstep * 4 + nt) * 64 + lane) * 8;
                bf16x8 bhi = *(const bf16x8*)bp;
                bf16x8 blo = *(const bf16x8*)(bp + 4096);
                acc[nt] = __builtin_amdgcn_mfma_f32_16x16x32_bf16(ahi, bhi, acc[nt], 0, 0, 0);
                acc[nt] = __builtin_amdgcn_mfma_f32_16x16x32_bf16(alo, bhi, acc[nt], 0, 0, 0);
                acc[nt] = __builtin_amdgcn_mfma_f32_16x16x32_bf16(ahi, blo, acc[nt], 0, 0, 0);
            }
        }
        // ---- bias + relu, repack h1 (hi|lo) into LDS in A-readable form ----
#pragma unroll
        for (int nt = 0; nt < 4; ++nt) {
            float b1v = b1[nt * 16 + r];
#pragma unroll
            for (int reg = 0; reg < 4; ++reg) {
                float v = fmaxf(acc[nt][reg] + b1v, 0.0f);
                __bf16 hi = (__bf16)v;
                __bf16 lo = (__bf16)(v - (float)hi);
                unsigned pk = ((unsigned)__builtin_bit_cast(unsigned short, hi) << 16)
                            | (unsigned)__builtin_bit_cast(unsigned short, lo);
                h1p[wv][q * 4 + reg][nt * 16 + r] = pk;
            }
            acc[nt] = (f32x4){0.f, 0.f, 0.f, 0.f};
        }
        // ---- Phase B2: GEMM2 from LDS ----
#pragma unroll
        for (int kstep = 0; kstep < 2; ++kstep) {
            uint4 p0 = *(const uint4*)&h1p[wv][r][kstep * 32 + q * 8];
            uint4 p1 = *(const uint4*)&h1p[wv][r][kstep * 32 + q * 8 + 4];
            unsigned pk[8] = {p0.x, p0.y, p0.z, p0.w, p1.x, p1.y, p1.z, p1.w};
            bf16x8 ahi, alo;
#pragma unroll
            for (int j = 0; j < 8; ++j) {
                ahi[j] = __builtin_bit_cast(__bf16, (unsigned short)(pk[j] >> 16));
                alo[j] = __builtin_bit_cast(__bf16, (unsigned short)(pk[j] & 0xffffu));
            }
#pragma unroll
            for (int nt = 0; nt < 4; ++nt) {
                const __bf16* bp = wf2 + ((kstep * 4 + nt) * 64 + lane) * 8;
                bf16x8 bhi = *(const bf16x8*)bp;
                bf16x8 blo = *(const bf16x8*)(bp + 4096);
                acc[nt] = __builtin_amdgcn_mfma_f32_16x16x32_bf16(ahi, bhi, acc[nt], 0, 0, 0);
                acc[nt] = __builtin_amdgcn_mfma_f32_16x16x32_bf16(alo, bhi, acc[nt], 0, 0, 0);
                acc[nt] = __builtin_amdgcn_mfma_f32_16x16x32_bf16(ahi, blo, acc[nt], 0, 0, 0);
            }
        }
        // ---- epilogue: bias + relu, store, BN partials ----
#pragma unroll
        for (int nt = 0; nt < 4; ++nt) {
            float b2v = b2[nt * 16 + r];
#pragma unroll
            for (int reg = 0; reg < 4; ++reg) {
                float v = fmaxf(acc[nt][reg] + b2v, 0.0f);
                h2out[(size_t)(node0 + q * 4 + reg) * 64 + nt * 16 + r] = v;
                bs[nt] += v;
                bq[nt] = fmaf(v, v, bq[nt]);
            }
        }
    }
    // ---- BN reduction: quads -> wave (shfl), waves -> block (LDS atomics) ----
    __syncthreads();                       // bnacc init visible to all waves
#pragma unroll
    for (int nt = 0; nt < 4; ++nt) {
        float s = bs[nt];
        s += __shfl_xor(s, 16);
        s += __shfl_xor(s, 32);
        float ss = bq[nt];
        ss += __shfl_xor(ss, 16);
        ss += __shfl_xor(ss, 32);
        if (q == 0) {
            atomicAdd(&bnacc[nt * 16 + r], s);
            atomicAdd(&bnacc[64 + nt * 16 + r], ss);
        }
    }
    __syncthreads();
    if (tid < 128) unsafeAtomicAdd(&sums[tid], bnacc[tid]);
}

// ---------------------------------------------------------------------------
// Segmented global mean pool (batch sorted): register-accumulate per graph,
// one atomic flush per boundary. Applies last layer's BN affine+relu on load.
// ---------------------------------------------------------------------------
__global__ __launch_bounds__(256) void pool_kernel(
    const float* __restrict__ h2, const float* __restrict__ sc,
    const int* __restrict__ batch,
    float* __restrict__ pooled, float* __restrict__ counts)
{
    const int lane = threadIdx.x & 63;
    const int w = blockIdx.x * 4 + (threadIdx.x >> 6);
    const int nw = POOL_BLOCKS * 4;
    const int npw = (N_NODES + nw - 1) / nw;
    int n0 = w * npw;
    if (n0 >= N_NODES) return;
    int n1 = n0 + npw;
    if (n1 > N_NODES) n1 = N_NODES;

    const float scale = sc[lane];
    const float shift = sc[64 + lane];

    int cur = batch[n0];
    float acc = 0.0f, cnt = 0.0f;
    for (int n = n0; n < n1; ++n) {
        int g = batch[n];                       // wave-uniform
        if (g != cur) {
            unsafeAtomicAdd(&pooled[cur * 64 + lane], acc);
            if (lane == 0) unsafeAtomicAdd(&counts[cur], cnt);
            acc = 0.0f; cnt = 0.0f; cur = g;
        }
        float v = h2[(size_t)n * 64 + lane];
        v = fmaxf(fmaf(v, scale, shift), 0.0f);
        acc += v;
        cnt += 1.0f;
    }
    unsafeAtomicAdd(&pooled[cur * 64 + lane], acc);
    if (lane == 0) unsafeAtomicAdd(&counts[cur], cnt);
}

// ---------------------------------------------------------------------------
// Final linear.
// ---------------------------------------------------------------------------
__global__ __launch_bounds__(256) void final_kernel(
    const float* __restrict__ pooled, const float* __restrict__ counts,
    const float* __restrict__ lin_w, const float* __restrict__ lin_b,
    float* __restrict__ out)
{
    int t = blockIdx.x * 256 + threadIdx.x;
    if (t >= N_GRAPHS * OUT_DIM) return;
    int g = t / OUT_DIM;
    int o = t - g * OUT_DIM;
    float acc = 0.0f;
#pragma unroll 8
    for (int d = 0; d < 64; ++d)
        acc = fmaf(pooled[g * 64 + d], lin_w[d * OUT_DIM + o], acc);
    float c = fmaxf(counts[g], 1.0f);
    out[t] = acc / c + lin_b[o];
}

extern "C" void kernel_launch(void* const* d_in, const int* in_sizes, int n_in,
                              void* d_out, int out_size, void* d_ws, size_t ws_size,
                              hipStream_t stream)
{
    const float* x0    = (const float*)d_in[0];
    const int*   ei    = (const int*)d_in[1];
    const int*   batch = (const int*)d_in[2];
    const float* w1    = (const float*)d_in[3];
    const float* b1    = (const float*)d_in[4];
    const float* w2    = (const float*)d_in[5];
    const float* b2    = (const float*)d_in[6];
    const float* gamma = (const float*)d_in[7];
    const float* beta  = (const float*)d_in[8];
    const float* eps_g = (const float*)d_in[9];
    const float* lin_w = (const float*)d_in[10];
    const float* lin_b = (const float*)d_in[11];
    float* out = (float*)d_out;

    // Workspace layout: everything that must start at 0 is contiguous
    // (SUMS..NSPILL) -> single memset.
    float* ws   = (float*)d_ws;
    float* A    = ws;                                // h2 ping, 6.4M floats
    float* B    = ws + (size_t)N_NODES * 64;         // h2 pong, 6.4M floats
    float* SUMS = ws + (size_t)2 * N_NODES * 64;     // 3*128   [zeroed]
    float* POOL = SUMS + 384;                        // 16384   [zeroed]
    float* CNT  = POOL + N_GRAPHS * 64;              // 256     [zeroed]
    int*   DEG    = (int*)(CNT + N_GRAPHS);          // 100000  [zeroed]
    int*   NSPILL = DEG + N_NODES;                   // 16      [zeroed]
    float* SC   = (float*)(NSPILL + 16);             // 3*128
    __bf16* WF  = (__bf16*)(SC + 384);               // 6*8192 bf16 = 96 KB
    int*   SPILL  = (int*)(WF + 6 * 8192);           // 2*SPILL_CAP
    int*   ESRC   = SPILL + 2 * SPILL_CAP;           // 24*N = 9.6 MB

    const size_t zero_bytes = (384 + N_GRAPHS * 64 + N_GRAPHS) * sizeof(float)
                            + (N_NODES + 16) * sizeof(int);
    const int fill_blocks = ((N_EDGES + 255) / 256) * NPART;  // 31256

    // ---- once per call: zeroing, weight fragments, edge fill ----
    hipMemsetAsync(SUMS, 0, zero_bytes, stream);
    wprep_kernel<<<6, 256, 0, stream>>>(w1, w2, WF);
    fill_kernel<<<fill_blocks, 256, 0, stream>>>(ei, DEG, ESRC, NSPILL, SPILL);

    // ---- 3 fused GIN layers (BN of layer L folded into layer L+1) ----
    layer_kernel<false><<<LAYER_BLOCKS, 256, 0, stream>>>(
        x0, nullptr, DEG, ESRC, NSPILL, SPILL, A,
        WF, WF + 8192, b1, b2, eps_g, 0, SUMS);
    bnprep_kernel<<<1, 64, 0, stream>>>(SUMS, gamma, beta, SC);

    layer_kernel<true><<<LAYER_BLOCKS, 256, 0, stream>>>(
        A, SC, DEG, ESRC, NSPILL, SPILL, B,
        WF + 16384, WF + 24576, b1 + 64, b2 + 64, eps_g, 1, SUMS + 128);
    bnprep_kernel<<<1, 64, 0, stream>>>(SUMS + 128, gamma + 64, beta + 64, SC + 128);

    layer_kernel<true><<<LAYER_BLOCKS, 256, 0, stream>>>(
        B, SC + 128, DEG, ESRC, NSPILL, SPILL, A,
        WF + 32768, WF + 40960, b1 + 128, b2 + 128, eps_g, 2, SUMS + 256);
    bnprep_kernel<<<1, 64, 0, stream>>>(SUMS + 256, gamma + 128, beta + 128, SC + 256);

    // ---- segmented pool (applies bn of L2) + linear ----
    pool_kernel<<<POOL_BLOCKS, 256, 0, stream>>>(A, SC + 256, batch, POOL, CNT);
    final_kernel<<<(N_GRAPHS * OUT_DIM + 255) / 256, 256, 0, stream>>>(
        POOL, CNT, lin_w, lin_b, out);
}

// Round 9
// 396.234 us; speedup vs baseline: 3.9908x; 1.0558x over previous
//
#include <hip/hip_runtime.h>
#include <hip/hip_bf16.h>

#define N_NODES 100000
#define N_EDGES 1000000
#define DIM 64
#define N_GRAPHS 256
#define OUT_DIM 10
#define BN_EPS 1e-5f

#define POOL_BLOCKS 512                      // 2048 waves
#define LAYER_BLOCKS ((N_NODES + 63) / 64)   // 1563
#define PAD 24                               // slots per node; P(deg>24)~4e-5
#define SPILL_CAP 8192
#define NPART 8                              // dst partitions (one per XCD)
#define PART_SZ ((N_NODES + NPART - 1) / NPART)   // 12500

typedef __bf16 bf16x8 __attribute__((ext_vector_type(8)));
typedef float f32x4 __attribute__((ext_vector_type(4)));

// ---------------------------------------------------------------------------
// Edge fill, XCD-partitioned (see R6): 8 block-replicas per 256-edge tile;
// replica part=blockIdx&7 handles only dst in its 12500-node range so each
// ESRC range is written by ~one XCD's L2 (kills cross-XCD dirty-line dup).
// ---------------------------------------------------------------------------
__global__ __launch_bounds__(256) void fill_kernel(
    const int* __restrict__ ei, int* __restrict__ deg,
    int* __restrict__ esrc, int* __restrict__ nspill, int* __restrict__ spill)
{
    const int part = blockIdx.x & (NPART - 1);
    const int e = (blockIdx.x >> 3) * 256 + threadIdx.x;
    if (e >= N_EDGES) return;
    int dst = ei[N_EDGES + e];
    int lo = part * PART_SZ;
    if (dst < lo || dst >= lo + PART_SZ) return;
    int src = ei[e];
    int pos = atomicAdd(&deg[dst], 1);
    if (pos < PAD) {
        esrc[dst * PAD + pos] = src;
    } else {
        int sp = atomicAdd(nspill, 1);
        if (sp < SPILL_CAP) { spill[2 * sp] = dst; spill[2 * sp + 1] = src; }
    }
}

// ---------------------------------------------------------------------------
// BN prep: per-dim affine from accumulated sum/sumsq.
// sc[0..63] = scale, sc[64..127] = shift.  y = relu(scale*v + shift)
// ---------------------------------------------------------------------------
__global__ __launch_bounds__(64) void bnprep_kernel(
    const float* __restrict__ sums, const float* __restrict__ gamma,
    const float* __restrict__ beta, float* __restrict__ sc)
{
    int d = threadIdx.x;
    const float inv_n = 1.0f / (float)N_NODES;
    float mean = sums[d] * inv_n;
    float m2 = sums[64 + d] * inv_n;
    float var = m2 - mean * mean;
    float scale = gamma[d] * rsqrtf(var + BN_EPS);
    sc[d] = scale;
    sc[64 + d] = fmaf(-mean, scale, beta[d]);
}

// ---------------------------------------------------------------------------
// Weight prep: split each 64x64 fp32 W into bf16 hi/lo, stored in MFMA
// B-fragment order: blob[(kstep*4+ntile)*64 + lane][j]; hi at +0, lo at +4096.
// ---------------------------------------------------------------------------
__global__ __launch_bounds__(256) void wprep_kernel(
    const float* __restrict__ w1, const float* __restrict__ w2,
    __bf16* __restrict__ wf)
{
    int L = blockIdx.x >> 1, mat = blockIdx.x & 1;
    const float* w = (mat ? w2 : w1) + L * 4096;
    __bf16* dst = wf + blockIdx.x * 8192;
#pragma unroll
    for (int r = 0; r < 2; ++r) {
        int idx = threadIdx.x + 256 * r;          // (kstep*4+nt)*64 + lane
        int lane = idx & 63;
        int kt = idx >> 6;
        int kstep = kt >> 2, nt = kt & 3;
        int n = nt * 16 + (lane & 15);
        int kbase = kstep * 32 + (lane >> 4) * 8;
#pragma unroll
        for (int j = 0; j < 8; ++j) {
            float v = w[(kbase + j) * 64 + n];
            __bf16 hi = (__bf16)v;
            dst[idx * 8 + j] = hi;
            dst[4096 + idx * 8 + j] = (__bf16)(v - (float)hi);
        }
    }
}

// ---------------------------------------------------------------------------
// FUSED GIN layer (R8): gather + spill + (1+eps)*self + 2-GEMM MLP + BN.
// vs R7: (1) hbuf/h1p aliased into ONE per-wave tile (A-frags for both ksteps
// are pulled into registers before the tile is overwritten with h1 — wave-
// lockstep program order makes this race-free) -> LDS 35.3->17.9 KB, 2x
// occupancy headroom. (2) Phase-A chain flattened: all 16 degs prefetched by
// one coalesced vector load + v_readlane (deg wave-uniform -> s_cbranch), and
// esrc index rows software-pipelined one node ahead, so row loads of
// successive nodes stay ~12-deep in flight continuously.
// ---------------------------------------------------------------------------
template <bool BN>
__global__ __launch_bounds__(256) void layer_kernel(
    const float* __restrict__ x, const float* __restrict__ sc,
    const int* __restrict__ deg, const int* __restrict__ esrc,
    const int* __restrict__ nspill, const int* __restrict__ spill,
    float* __restrict__ h2out,
    const __bf16* __restrict__ wf1, const __bf16* __restrict__ wf2,
    const float* __restrict__ b1, const float* __restrict__ b2,
    const float* __restrict__ eps_all, int layer,
    float* __restrict__ sums)
{
    __shared__ __attribute__((aligned(16))) unsigned tile[4][16][68];
    __shared__ float bnacc[128];

    const int tid = threadIdx.x;
    const int lane = tid & 63;
    const int wv = tid >> 6;
    const int q = lane >> 4;      // quad
    const int r = lane & 15;      // row-in-quad / col
    const int node0 = blockIdx.x * 64 + wv * 16;
    const bool active = node0 < N_NODES;   // 16-node tiles never straddle N

    if (tid < 128) bnacc[tid] = 0.0f;

    f32x4 acc[4];
    float bs[4], bq[4];
#pragma unroll
    for (int nt = 0; nt < 4; ++nt) {
        acc[nt] = (f32x4){0.f, 0.f, 0.f, 0.f};
        bs[nt] = 0.0f; bq[nt] = 0.0f;
    }

    float scale = 1.0f, shift = 0.0f;
    if (BN) { scale = sc[lane]; shift = sc[64 + lane]; }

    if (active) {
        const float epsv = 1.0f + eps_all[layer];

        // ---- Phase A: gather + self, lane = dim ----
        // Prefetch all 16 degrees (one coalesced load, then readlane).
        int dvec = 0;
        if (lane < 16) dvec = deg[node0 + lane];
        // Prefetch idx row for node 0.
        uint4 nf0, nf1, nf2;
        {
            const uint4* ip = (const uint4*)(esrc + (size_t)node0 * PAD);
            nf0 = ip[0]; nf1 = ip[1]; nf2 = ip[2];
        }
        for (int i = 0; i < 16; ++i) {
            const uint4 c0 = nf0, c1 = nf1, c2 = nf2;
            if (i < 15) {   // issue next node's idx loads before consuming
                const uint4* ip = (const uint4*)(esrc + (size_t)(node0 + i + 1) * PAD);
                nf0 = ip[0]; nf1 = ip[1]; nf2 = ip[2];
            }
            const int n = node0 + i;
            const int dfull = __builtin_amdgcn_readlane(dvec, i);  // wave-uniform
            const int d = min(dfull, PAD);

            float xv = x[(size_t)n * 64 + lane];
            if (BN) xv = fmaxf(fmaf(xv, scale, shift), 0.0f);
            float hval = epsv * xv;

            {   // chunk 0: idx already in registers
                unsigned idx[12] = {c0.x, c0.y, c0.z, c0.w, c1.x, c1.y,
                                    c1.z, c1.w, c2.x, c2.y, c2.z, c2.w};
                float v[12];
#pragma unroll
                for (int j = 0; j < 12; ++j) {
                    unsigned s = idx[j];
                    s = (s < (unsigned)N_NODES) ? s : 0u;   // garbage past d
                    v[j] = x[(size_t)s * 64 + lane];
                }
#pragma unroll
                for (int j = 0; j < 12; ++j) {
                    float t = v[j];
                    if (BN) t = fmaxf(fmaf(t, scale, shift), 0.0f);
                    hval += (j < d) ? t : 0.0f;
                }
            }
            if (d > 12) {   // wave-uniform branch, ~25% of nodes
                const int* ep = esrc + (size_t)n * PAD + 12;
                float v[12];
#pragma unroll
                for (int j = 0; j < 12; ++j) {
                    unsigned s = (unsigned)ep[j];
                    s = (s < (unsigned)N_NODES) ? s : 0u;
                    v[j] = x[(size_t)s * 64 + lane];
                }
#pragma unroll
                for (int j = 0; j < 12; ++j) {
                    float t = v[j];
                    if (BN) t = fmaxf(fmaf(t, scale, shift), 0.0f);
                    hval += (12 + j < d) ? t : 0.0f;
                }
            }
            if (dfull > PAD) {   // ultra-rare: scan tiny spill list
                int ns = min(*nspill, SPILL_CAP);
                for (int e = 0; e < ns; ++e) {
                    if (spill[2 * e] == n) {
                        float t = x[(size_t)spill[2 * e + 1] * 64 + lane];
                        if (BN) t = fmaxf(fmaf(t, scale, shift), 0.0f);
                        hval += t;
                    }
                }
            }
            __bf16 hi = (__bf16)hval;
            __bf16 lo = (__bf16)(hval - (float)hi);
            tile[wv][i][lane] = ((unsigned)__builtin_bit_cast(unsigned short, hi) << 16)
                              | (unsigned)__builtin_bit_cast(unsigned short, lo);
        }

        // ---- Phase B1: pull BOTH ksteps' A-frags into regs, then GEMM1 ----
        uint4 f0 = *(const uint4*)&tile[wv][r][q * 8];
        uint4 f1 = *(const uint4*)&tile[wv][r][q * 8 + 4];
        uint4 f2 = *(const uint4*)&tile[wv][r][32 + q * 8];
        uint4 f3 = *(const uint4*)&tile[wv][r][32 + q * 8 + 4];
#pragma unroll
        for (int kstep = 0; kstep < 2; ++kstep) {
            uint4 p0 = kstep ? f2 : f0;
            uint4 p1 = kstep ? f3 : f1;
            unsigned pk[8] = {p0.x, p0.y, p0.z, p0.w, p1.x, p1.y, p1.z, p1.w};
            bf16x8 ahi, alo;
#pragma unroll
            for (int j = 0; j < 8; ++j) {
                ahi[j] = __builtin_bit_cast(__bf16, (unsigned short)(pk[j] >> 16));
                alo[j] = __builtin_bit_cast(__bf16, (unsigned short)(pk[j] & 0xffffu));
            }
#pragma unroll
            for (int nt = 0; nt < 4; ++nt) {
                const __bf16* bp = wf1 + ((kstep * 4 + nt) * 64 + lane) * 8;
                bf16x8 bhi = *(const bf16x8*)bp;
                bf16x8 blo = *(const bf16x8*)(bp + 4096);
                acc[nt] = __builtin_amdgcn_mfma_f32_16x16x32_bf16(ahi, bhi, acc[nt], 0, 0, 0);
                acc[nt] = __builtin_amdgcn_mfma_f32_16x16x32_bf16(alo, bhi, acc[nt], 0, 0, 0);
                acc[nt] = __builtin_amdgcn_mfma_f32_16x16x32_bf16(ahi, blo, acc[nt], 0, 0, 0);
            }
        }
        // ---- bias + relu, repack h1 (hi|lo) into the SAME tile ----
        // (all lanes of this wave have read f0..f3 above; wave-lockstep makes
        //  the overwrite race-free)
#pragma unroll
        for (int nt = 0; nt < 4; ++nt) {
            float b1v = b1[nt * 16 + r];
#pragma unroll
            for (int reg = 0; reg < 4; ++reg) {
                float v = fmaxf(acc[nt][reg] + b1v, 0.0f);
                __bf16 hi = (__bf16)v;
                __bf16 lo = (__bf16)(v - (float)hi);
                unsigned pk = ((unsigned)__builtin_bit_cast(unsigned short, hi) << 16)
                            | (unsigned)__builtin_bit_cast(unsigned short, lo);
                tile[wv][q * 4 + reg][nt * 16 + r] = pk;
            }
            acc[nt] = (f32x4){0.f, 0.f, 0.f, 0.f};
        }
        // ---- Phase B2: GEMM2 from tile ----
#pragma unroll
        for (int kstep = 0; kstep < 2; ++kstep) {
            uint4 p0 = *(const uint4*)&tile[wv][r][kstep * 32 + q * 8];
            uint4 p1 = *(const uint4*)&tile[wv][r][kstep * 32 + q * 8 + 4];
            unsigned pk[8] = {p0.x, p0.y, p0.z, p0.w, p1.x, p1.y, p1.z, p1.w};
            bf16x8 ahi, alo;
#pragma unroll
            for (int j = 0; j < 8; ++j) {
                ahi[j] = __builtin_bit_cast(__bf16, (unsigned short)(pk[j] >> 16));
                alo[j] = __builtin_bit_cast(__bf16, (unsigned short)(pk[j] & 0xffffu));
            }
#pragma unroll
            for (int nt = 0; nt < 4; ++nt) {
                const __bf16* bp = wf2 + ((kstep * 4 + nt) * 64 + lane) * 8;
                bf16x8 bhi = *(const bf16x8*)bp;
                bf16x8 blo = *(const bf16x8*)(bp + 4096);
                acc[nt] = __builtin_amdgcn_mfma_f32_16x16x32_bf16(ahi, bhi, acc[nt], 0, 0, 0);
                acc[nt] = __builtin_amdgcn_mfma_f32_16x16x32_bf16(alo, bhi, acc[nt], 0, 0, 0);
                acc[nt] = __builtin_amdgcn_mfma_f32_16x16x32_bf16(ahi, blo, acc[nt], 0, 0, 0);
            }
        }
        // ---- epilogue: bias + relu, store, BN partials ----
#pragma unroll
        for (int nt = 0; nt < 4; ++nt) {
            float b2v = b2[nt * 16 + r];
#pragma unroll
            for (int reg = 0; reg < 4; ++reg) {
                float v = fmaxf(acc[nt][reg] + b2v, 0.0f);
                h2out[(size_t)(node0 + q * 4 + reg) * 64 + nt * 16 + r] = v;
                bs[nt] += v;
                bq[nt] = fmaf(v, v, bq[nt]);
            }
        }
    }
    // ---- BN reduction: quads -> wave (shfl), waves -> block (LDS atomics) ----
    __syncthreads();                       // bnacc init visible to all waves
#pragma unroll
    for (int nt = 0; nt < 4; ++nt) {
        float s = bs[nt];
        s += __shfl_xor(s, 16);
        s += __shfl_xor(s, 32);
        float ss = bq[nt];
        ss += __shfl_xor(ss, 16);
        ss += __shfl_xor(ss, 32);
        if (q == 0) {
            atomicAdd(&bnacc[nt * 16 + r], s);
            atomicAdd(&bnacc[64 + nt * 16 + r], ss);
        }
    }
    __syncthreads();
    if (tid < 128) unsafeAtomicAdd(&sums[tid], bnacc[tid]);
}

// ---------------------------------------------------------------------------
// Segmented global mean pool (batch sorted): register-accumulate per graph,
// one atomic flush per boundary. Applies last layer's BN affine+relu on load.
// ---------------------------------------------------------------------------
__global__ __launch_bounds__(256) void pool_kernel(
    const float* __restrict__ h2, const float* __restrict__ sc,
    const int* __restrict__ batch,
    float* __restrict__ pooled, float* __restrict__ counts)
{
    const int lane = threadIdx.x & 63;
    const int w = blockIdx.x * 4 + (threadIdx.x >> 6);
    const int nw = POOL_BLOCKS * 4;
    const int npw = (N_NODES + nw - 1) / nw;
    int n0 = w * npw;
    if (n0 >= N_NODES) return;
    int n1 = n0 + npw;
    if (n1 > N_NODES) n1 = N_NODES;

    const float scale = sc[lane];
    const float shift = sc[64 + lane];

    int cur = batch[n0];
    float acc = 0.0f, cnt = 0.0f;
    for (int n = n0; n < n1; ++n) {
        int g = batch[n];                       // wave-uniform
        if (g != cur) {
            unsafeAtomicAdd(&pooled[cur * 64 + lane], acc);
            if (lane == 0) unsafeAtomicAdd(&counts[cur], cnt);
            acc = 0.0f; cnt = 0.0f; cur = g;
        }
        float v = h2[(size_t)n * 64 + lane];
        v = fmaxf(fmaf(v, scale, shift), 0.0f);
        acc += v;
        cnt += 1.0f;
    }
    unsafeAtomicAdd(&pooled[cur * 64 + lane], acc);
    if (lane == 0) unsafeAtomicAdd(&counts[cur], cnt);
}

// ---------------------------------------------------------------------------
// Final linear.
// ---------------------------------------------------------------------------
__global__ __launch_bounds__(256) void final_kernel(
    const float* __restrict__ pooled, const float* __restrict__ counts,
    const float* __restrict__ lin_w, const float* __restrict__ lin_b,
    float* __restrict__ out)
{
    int t = blockIdx.x * 256 + threadIdx.x;
    if (t >= N_GRAPHS * OUT_DIM) return;
    int g = t / OUT_DIM;
    int o = t - g * OUT_DIM;
    float acc = 0.0f;
#pragma unroll 8
    for (int d = 0; d < 64; ++d)
        acc = fmaf(pooled[g * 64 + d], lin_w[d * OUT_DIM + o], acc);
    float c = fmaxf(counts[g], 1.0f);
    out[t] = acc / c + lin_b[o];
}

extern "C" void kernel_launch(void* const* d_in, const int* in_sizes, int n_in,
                              void* d_out, int out_size, void* d_ws, size_t ws_size,
                              hipStream_t stream)
{
    const float* x0    = (const float*)d_in[0];
    const int*   ei    = (const int*)d_in[1];
    const int*   batch = (const int*)d_in[2];
    const float* w1    = (const float*)d_in[3];
    const float* b1    = (const float*)d_in[4];
    const float* w2    = (const float*)d_in[5];
    const float* b2    = (const float*)d_in[6];
    const float* gamma = (const float*)d_in[7];
    const float* beta  = (const float*)d_in[8];
    const float* eps_g = (const float*)d_in[9];
    const float* lin_w = (const float*)d_in[10];
    const float* lin_b = (const float*)d_in[11];
    float* out = (float*)d_out;

    // Workspace layout: everything that must start at 0 is contiguous
    // (SUMS..NSPILL) -> single memset.
    float* ws   = (float*)d_ws;
    float* A    = ws;                                // h2 ping, 6.4M floats
    float* B    = ws + (size_t)N_NODES * 64;         // h2 pong, 6.4M floats
    float* SUMS = ws + (size_t)2 * N_NODES * 64;     // 3*128   [zeroed]
    float* POOL = SUMS + 384;                        // 16384   [zeroed]
    float* CNT  = POOL + N_GRAPHS * 64;              // 256     [zeroed]
    int*   DEG    = (int*)(CNT + N_GRAPHS);          // 100000  [zeroed]
    int*   NSPILL = DEG + N_NODES;                   // 16      [zeroed]
    float* SC   = (float*)(NSPILL + 16);             // 3*128
    __bf16* WF  = (__bf16*)(SC + 384);               // 6*8192 bf16 = 96 KB
    int*   SPILL  = (int*)(WF + 6 * 8192);           // 2*SPILL_CAP
    int*   ESRC   = SPILL + 2 * SPILL_CAP;           // 24*N = 9.6 MB

    const size_t zero_bytes = (384 + N_GRAPHS * 64 + N_GRAPHS) * sizeof(float)
                            + (N_NODES + 16) * sizeof(int);
    const int fill_blocks = ((N_EDGES + 255) / 256) * NPART;  // 31256

    // ---- once per call: zeroing, weight fragments, edge fill ----
    hipMemsetAsync(SUMS, 0, zero_bytes, stream);
    wprep_kernel<<<6, 256, 0, stream>>>(w1, w2, WF);
    fill_kernel<<<fill_blocks, 256, 0, stream>>>(ei, DEG, ESRC, NSPILL, SPILL);

    // ---- 3 fused GIN layers (BN of layer L folded into layer L+1) ----
    layer_kernel<false><<<LAYER_BLOCKS, 256, 0, stream>>>(
        x0, nullptr, DEG, ESRC, NSPILL, SPILL, A,
        WF, WF + 8192, b1, b2, eps_g, 0, SUMS);
    bnprep_kernel<<<1, 64, 0, stream>>>(SUMS, gamma, beta, SC);

    layer_kernel<true><<<LAYER_BLOCKS, 256, 0, stream>>>(
        A, SC, DEG, ESRC, NSPILL, SPILL, B,
        WF + 16384, WF + 24576, b1 + 64, b2 + 64, eps_g, 1, SUMS + 128);
    bnprep_kernel<<<1, 64, 0, stream>>>(SUMS + 128, gamma + 64, beta + 64, SC + 128);

    layer_kernel<true><<<LAYER_BLOCKS, 256, 0, stream>>>(
        B, SC + 128, DEG, ESRC, NSPILL, SPILL, A,
        WF + 32768, WF + 40960, b1 + 128, b2 + 128, eps_g, 2, SUMS + 256);
    bnprep_kernel<<<1, 64, 0, stream>>>(SUMS + 256, gamma + 128, beta + 128, SC + 256);

    // ---- segmented pool (applies bn of L2) + linear ----
    pool_kernel<<<POOL_BLOCKS, 256, 0, stream>>>(A, SC + 256, batch, POOL, CNT);
    final_kernel<<<(N_GRAPHS * OUT_DIM + 255) / 256, 256, 0, stream>>>(
        POOL, CNT, lin_w, lin_b, out);
}